// Round 2
// baseline (1116.403 us; speedup 1.0000x reference)
//
#include <hip/hip_runtime.h>
#include <math.h>

#define Bsz 4
#define DIM 512
#define LEN 4096
#define DST 16
#define DIN 1024
#define NCH 32    // number of chunks over L
#define CHL 128   // chunk length (NCH*CHL == LEN)

typedef unsigned short ushort_t;
typedef unsigned int uint_t;

__device__ __forceinline__ float sigmoidf_(float x){ return 1.0f/(1.0f+__expf(-x)); }
__device__ __forceinline__ float softplusf_(float x){ return x > 20.0f ? x : log1pf(__expf(x)); }
__device__ __forceinline__ float bf2f(ushort_t u){ return __uint_as_float(((uint_t)u) << 16); }
__device__ __forceinline__ ushort_t f2bf(float f){
  uint_t x = __float_as_uint(f);
  uint_t r = (x + 0x7FFFu + ((x >> 16) & 1u)) >> 16;
  return (ushort_t)r;
}

// ---------------- LayerNorm stats: mu, rstd per (b,l) ----------------
__global__ __launch_bounds__(256) void ln_stats_k(const float* __restrict__ x,
                                                  float* __restrict__ mu, float* __restrict__ rs){
  int bid = blockIdx.x;            // 256 blocks: b (4) x l-group (64)
  int b = bid >> 6;
  int lg = bid & 63;
  int lane = threadIdx.x & 63;
  int g = threadIdx.x >> 6;        // 0..3
  int l = lg*64 + lane;
  const float* xb = x + (size_t)b*DIM*LEN + l;
  float s = 0.f, sq = 0.f;
  for(int d = g*128; d < g*128 + 128; ++d){
    float v = xb[(size_t)d*LEN];
    s += v; sq += v*v;
  }
  __shared__ float rsum[4][64], rsq[4][64];
  rsum[g][lane] = s; rsq[g][lane] = sq;
  __syncthreads();
  if(threadIdx.x < 64){
    float ts = 0.f, tq = 0.f;
    for(int gg=0; gg<4; ++gg){ ts += rsum[gg][lane]; tq += rsq[gg][lane]; }
    float m = ts * (1.0f/DIM);
    float var = tq * (1.0f/DIM) - m*m;
    mu[b*LEN + l] = m;
    rs[b*LEN + l] = rsqrtf(var + 1e-5f);
  }
}

// ---------------- GEMM1: LN(x)[m,k] * W_in[n,k]; n<1024 -> xin fp32, n>=1024 -> silu -> sz bf16 ----------------
__global__ __launch_bounds__(256) void gemm1_k(const float* __restrict__ x,
    const float* __restrict__ mu, const float* __restrict__ rs,
    const float* __restrict__ lnw, const float* __restrict__ lnb,
    const float* __restrict__ Win, float* __restrict__ xin, ushort_t* __restrict__ sz){
  __shared__ __align__(16) float As[16*132];
  __shared__ __align__(16) float Bs[16*132];
  __shared__ float lnw_s[DIM], lnb_s[DIM];
  int tid = threadIdx.x;
  int n0 = blockIdx.x * 128;       // 0..1920 over 2048
  int m0 = blockIdx.y * 128;
  int b  = m0 / LEN;
  int l0 = m0 % LEN;
  for(int i=tid;i<DIM;i+=256){ lnw_s[i]=lnw[i]; lnb_s[i]=lnb[i]; }
  int la = tid & 127;
  int hi = tid >> 7;
  float mul_ = mu[b*LEN + l0 + la];
  float rsl  = rs[b*LEN + l0 + la];
  int q  = tid & 3;
  int nn = tid >> 2;               // 0..63
  int tx = tid & 15, ty = tid >> 4;
  float acc[2][2][4][4] = {};
  const float* xb = x + (size_t)b*DIM*LEN;
  for(int k0=0; k0<DIM; k0+=16){
    __syncthreads();
    #pragma unroll
    for(int r=0;r<8;r++){
      int ki = r*2 + hi;
      float v = xb[(size_t)(k0+ki)*LEN + l0 + la];
      As[ki*132 + la] = (v - mul_)*rsl*lnw_s[k0+ki] + lnb_s[k0+ki];
    }
    #pragma unroll
    for(int r=0;r<2;r++){
      int ni = nn + r*64;
      float4 w = *(const float4*)&Win[(size_t)(n0+ni)*DIM + k0 + q*4];
      Bs[(q*4+0)*132 + ni] = w.x;
      Bs[(q*4+1)*132 + ni] = w.y;
      Bs[(q*4+2)*132 + ni] = w.z;
      Bs[(q*4+3)*132 + ni] = w.w;
    }
    __syncthreads();
    #pragma unroll
    for(int kk=0;kk<16;kk++){
      float4 a0 = *(const float4*)&As[kk*132 + ty*4];
      float4 a1 = *(const float4*)&As[kk*132 + 64 + ty*4];
      float4 b0 = *(const float4*)&Bs[kk*132 + tx*4];
      float4 b1 = *(const float4*)&Bs[kk*132 + 64 + tx*4];
      float av[2][4] = {{a0.x,a0.y,a0.z,a0.w},{a1.x,a1.y,a1.z,a1.w}};
      float bv[2][4] = {{b0.x,b0.y,b0.z,b0.w},{b1.x,b1.y,b1.z,b1.w}};
      #pragma unroll
      for(int mg=0;mg<2;mg++)
        #pragma unroll
        for(int i=0;i<4;i++)
          #pragma unroll
          for(int ng=0;ng<2;ng++)
            #pragma unroll
            for(int j=0;j<4;j++)
              acc[mg][ng][i][j] += av[mg][i]*bv[ng][j];
    }
  }
  bool is_z = (n0 >= 1024);
  #pragma unroll
  for(int mg=0;mg<2;mg++)
    #pragma unroll
    for(int i=0;i<4;i++){
      int m = m0 + mg*64 + ty*4 + i;
      #pragma unroll
      for(int ng=0;ng<2;ng++){
        int n = n0 + ng*64 + tx*4;
        if(!is_z){
          float4 v = {acc[mg][ng][i][0],acc[mg][ng][i][1],acc[mg][ng][i][2],acc[mg][ng][i][3]};
          *(float4*)&xin[(size_t)m*DIN + n] = v;
        } else {
          ushort4 v;
          float a0 = acc[mg][ng][i][0], a1 = acc[mg][ng][i][1];
          float a2 = acc[mg][ng][i][2], a3 = acc[mg][ng][i][3];
          v.x = f2bf(a0 * sigmoidf_(a0));
          v.y = f2bf(a1 * sigmoidf_(a1));
          v.z = f2bf(a2 * sigmoidf_(a2));
          v.w = f2bf(a3 * sigmoidf_(a3));
          *(ushort4*)&sz[(size_t)m*DIN + (n - 1024)] = v;
        }
      }
    }
}

// ---------------- conv1d (depthwise, causal, k=4) + SiLU -> u bf16 [b,l,d] ----------------
__global__ __launch_bounds__(256) void conv_silu_k(const float* __restrict__ xin,
    const float* __restrict__ cw, const float* __restrict__ cb, ushort_t* __restrict__ u){
  int idx = blockIdx.x*256 + threadIdx.x;   // == (b*LEN+l)*DIN + d
  int d = idx & 1023;
  int r = idx >> 10;
  int l = r & 4095;
  int b = r >> 12;
  float acc = cb[d];
  const float* base = xin + (size_t)b*LEN*DIN + d;
  #pragma unroll
  for(int j=0;j<4;j++){
    int ls = l - 3 + j;
    if(ls >= 0) acc += base[(size_t)ls*DIN] * cw[d*4+j];
  }
  u[idx] = f2bf(acc * sigmoidf_(acc));
}

// ---------------- GEMM2: dbl[m,n] = u[m,k]*Wxp[n,k], M=16384 N=64 K=1024 ----------------
__global__ __launch_bounds__(256) void gemm2_k(const ushort_t* __restrict__ u,
    const float* __restrict__ Wxp, float* __restrict__ dbl){
  __shared__ __align__(16) float As[16*68];
  __shared__ __align__(16) float Bs[16*68];
  int tid = threadIdx.x;
  int m0 = blockIdx.x*64;
  int q = tid & 3, row = tid >> 2;
  int tx = tid & 15, ty = tid >> 4;
  float acc[4][4] = {};
  for(int k0=0;k0<DIN;k0+=16){
    __syncthreads();
    {
      ushort4 a = *(const ushort4*)&u[(size_t)(m0+row)*DIN + k0 + q*4];
      As[(q*4+0)*68+row]=bf2f(a.x); As[(q*4+1)*68+row]=bf2f(a.y);
      As[(q*4+2)*68+row]=bf2f(a.z); As[(q*4+3)*68+row]=bf2f(a.w);
      float4 w = *(const float4*)&Wxp[(size_t)row*DIN + k0 + q*4];
      Bs[(q*4+0)*68+row]=w.x; Bs[(q*4+1)*68+row]=w.y; Bs[(q*4+2)*68+row]=w.z; Bs[(q*4+3)*68+row]=w.w;
    }
    __syncthreads();
    #pragma unroll
    for(int kk=0;kk<16;kk++){
      float4 a = *(const float4*)&As[kk*68 + ty*4];
      float4 bv = *(const float4*)&Bs[kk*68 + tx*4];
      float av[4]={a.x,a.y,a.z,a.w}, bb[4]={bv.x,bv.y,bv.z,bv.w};
      #pragma unroll
      for(int i=0;i<4;i++)
        #pragma unroll
        for(int j=0;j<4;j++) acc[i][j] += av[i]*bb[j];
    }
  }
  #pragma unroll
  for(int i=0;i<4;i++){
    float4 v = {acc[i][0],acc[i][1],acc[i][2],acc[i][3]};
    *(float4*)&dbl[(size_t)(m0+ty*4+i)*64 + tx*4] = v;
  }
}

// ---------------- GEMM3: delta[m,n] = softplus(dt[m,k]*Wdt[n,k] + bdt[n]), K=32; delta -> xin buffer ----------------
__global__ __launch_bounds__(256) void gemm3_k(const float* __restrict__ dbl,
    const float* __restrict__ Wdt, const float* __restrict__ bdt, float* __restrict__ delta){
  __shared__ __align__(16) float As[16*68];
  __shared__ __align__(16) float Bs[16*68];
  int tid = threadIdx.x;
  int n0 = blockIdx.x*64, m0 = blockIdx.y*64;
  int q = tid & 3, row = tid >> 2;
  int tx = tid & 15, ty = tid >> 4;
  float acc[4][4] = {};
  for(int k0=0;k0<32;k0+=16){
    __syncthreads();
    {
      float4 a = *(const float4*)&dbl[(size_t)(m0+row)*64 + k0 + q*4];   // dt = dbl[:, :32]
      As[(q*4+0)*68+row]=a.x; As[(q*4+1)*68+row]=a.y; As[(q*4+2)*68+row]=a.z; As[(q*4+3)*68+row]=a.w;
      float4 w = *(const float4*)&Wdt[(size_t)(n0+row)*32 + k0 + q*4];
      Bs[(q*4+0)*68+row]=w.x; Bs[(q*4+1)*68+row]=w.y; Bs[(q*4+2)*68+row]=w.z; Bs[(q*4+3)*68+row]=w.w;
    }
    __syncthreads();
    #pragma unroll
    for(int kk=0;kk<16;kk++){
      float4 a = *(const float4*)&As[kk*68 + ty*4];
      float4 bv = *(const float4*)&Bs[kk*68 + tx*4];
      float av[4]={a.x,a.y,a.z,a.w}, bb[4]={bv.x,bv.y,bv.z,bv.w};
      #pragma unroll
      for(int i=0;i<4;i++)
        #pragma unroll
        for(int j=0;j<4;j++) acc[i][j] += av[i]*bb[j];
    }
  }
  #pragma unroll
  for(int i=0;i<4;i++){
    float4 v;
    v.x = softplusf_(acc[i][0] + bdt[n0+tx*4+0]);
    v.y = softplusf_(acc[i][1] + bdt[n0+tx*4+1]);
    v.z = softplusf_(acc[i][2] + bdt[n0+tx*4+2]);
    v.w = softplusf_(acc[i][3] + bdt[n0+tx*4+3]);
    *(float4*)&delta[(size_t)(m0+ty*4+i)*DIN + n0 + tx*4] = v;
  }
}

// ---------------- scan phase A: per-chunk (prod a, local end state) ----------------
__global__ __launch_bounds__(256) void scanA_k(const float* __restrict__ delta,
    const ushort_t* __restrict__ u, const float* __restrict__ dbl, const float* __restrict__ Alog,
    float* __restrict__ P, float* __restrict__ E){
  int bid = blockIdx.x;            // Bsz * 4 * NCH = 512
  int c = bid & (NCH-1);
  int dblk = (bid >> 5) & 3;
  int b = bid >> 7;
  int d = dblk*256 + threadIdx.x;
  float nA[DST], Ps[DST], Es[DST];
  #pragma unroll
  for(int s=0;s<DST;s++){ nA[s] = -__expf(Alog[d*DST+s]); Ps[s]=1.f; Es[s]=0.f; }
  int t0 = c*CHL;
  const float* dl = delta + (size_t)b*LEN*DIN + d;
  const ushort_t* uu = u  + (size_t)b*LEN*DIN + d;
  const float* bc = dbl   + (size_t)b*LEN*64 + 32;
  for(int t=t0; t<t0+CHL; ++t){
    float dv = dl[(size_t)t*DIN];
    float uv = bf2f(uu[(size_t)t*DIN]);
    float du = dv*uv;
    const float* Bt = bc + (size_t)t*64;
    #pragma unroll
    for(int s=0;s<DST;s++){
      float a = __expf(dv * nA[s]);
      Ps[s] *= a;
      Es[s] = a*Es[s] + du*Bt[s];
    }
  }
  size_t o = (size_t)(b*NCH + c)*DST*DIN + d;
  #pragma unroll
  for(int s=0;s<DST;s++){ P[o + (size_t)s*DIN] = Ps[s]; E[o + (size_t)s*DIN] = Es[s]; }
}

// ---------------- scan phase B: combine chunk boundaries; Hs written in-place over E ----------------
__global__ __launch_bounds__(256) void scanB_k(const float* __restrict__ P, float* __restrict__ E){
  int g = blockIdx.x*256 + threadIdx.x;   // 65536 = Bsz*DST*DIN
  int d = g & 1023;
  int s = (g >> 10) & 15;
  int b = g >> 14;
  float h = 0.f;
  for(int c=0;c<NCH;c++){
    size_t o = (size_t)((b*NCH + c)*DST + s)*DIN + d;
    float p = P[o], e = E[o];
    E[o] = h;                 // initial state for chunk c
    h = p*h + e;
  }
}

// ---------------- scan phase C: replay chunk, y = (scan + u*D) * sz, in-place over delta ----------------
__global__ __launch_bounds__(256) void scanC_k(float* __restrict__ delta,
    const ushort_t* __restrict__ u, const float* __restrict__ dbl, const float* __restrict__ Alog,
    const float* __restrict__ Hs, const float* __restrict__ Dp, const ushort_t* __restrict__ sz){
  int bid = blockIdx.x;
  int c = bid & (NCH-1);
  int dblk = (bid >> 5) & 3;
  int b = bid >> 7;
  int d = dblk*256 + threadIdx.x;
  float nA[DST], h[DST];
  size_t ho = (size_t)(b*NCH + c)*DST*DIN + d;
  #pragma unroll
  for(int s=0;s<DST;s++){ nA[s] = -__expf(Alog[d*DST+s]); h[s] = Hs[ho + (size_t)s*DIN]; }
  float Dv = Dp[d];
  int t0 = c*CHL;
  float* dl = delta + (size_t)b*LEN*DIN + d;
  const ushort_t* uu = u + (size_t)b*LEN*DIN + d;
  const float* bc = dbl + (size_t)b*LEN*64 + 32;
  const ushort_t* zz = sz + (size_t)b*LEN*DIN + d;
  for(int t=t0; t<t0+CHL; ++t){
    float dv = dl[(size_t)t*DIN];
    float uv = bf2f(uu[(size_t)t*DIN]);
    float du = dv*uv;
    const float* Bt = bc + (size_t)t*64;
    const float* Ct = Bt + DST;
    float y = 0.f;
    #pragma unroll
    for(int s=0;s<DST;s++){
      float a = __expf(dv*nA[s]);
      h[s] = a*h[s] + du*Bt[s];
      y += h[s]*Ct[s];
    }
    y += uv*Dv;
    y *= bf2f(zz[(size_t)t*DIN]);
    dl[(size_t)t*DIN] = y;
  }
}

// ---------------- GEMM4: out[b,n,l] = y[m,k]*Wout[n,k], transposed store ----------------
__global__ __launch_bounds__(256) void gemm4_k(const float* __restrict__ y,
    const float* __restrict__ Wout, float* __restrict__ out){
  __shared__ __align__(16) float As[16*132];
  __shared__ __align__(16) float Bs[16*132];
  int tid = threadIdx.x;
  int n0 = blockIdx.x*128, m0 = blockIdx.y*128;
  int q = tid & 3, row = tid >> 2;   // row 0..63
  int tx = tid & 15, ty = tid >> 4;
  float acc[2][2][4][4] = {};
  for(int k0=0;k0<DIN;k0+=16){
    __syncthreads();
    #pragma unroll
    for(int r=0;r<2;r++){
      int mi = row + r*64;
      float4 a = *(const float4*)&y[(size_t)(m0+mi)*DIN + k0 + q*4];
      As[(q*4+0)*132+mi]=a.x; As[(q*4+1)*132+mi]=a.y; As[(q*4+2)*132+mi]=a.z; As[(q*4+3)*132+mi]=a.w;
      int ni = row + r*64;
      float4 w = *(const float4*)&Wout[(size_t)(n0+ni)*DIN + k0 + q*4];
      Bs[(q*4+0)*132+ni]=w.x; Bs[(q*4+1)*132+ni]=w.y; Bs[(q*4+2)*132+ni]=w.z; Bs[(q*4+3)*132+ni]=w.w;
    }
    __syncthreads();
    #pragma unroll
    for(int kk=0;kk<16;kk++){
      float4 a0 = *(const float4*)&As[kk*132 + ty*4];
      float4 a1 = *(const float4*)&As[kk*132 + 64 + ty*4];
      float4 b0 = *(const float4*)&Bs[kk*132 + tx*4];
      float4 b1 = *(const float4*)&Bs[kk*132 + 64 + tx*4];
      float av[2][4] = {{a0.x,a0.y,a0.z,a0.w},{a1.x,a1.y,a1.z,a1.w}};
      float bv[2][4] = {{b0.x,b0.y,b0.z,b0.w},{b1.x,b1.y,b1.z,b1.w}};
      #pragma unroll
      for(int mg=0;mg<2;mg++)
        #pragma unroll
        for(int i=0;i<4;i++)
          #pragma unroll
          for(int ng=0;ng<2;ng++)
            #pragma unroll
            for(int j=0;j<4;j++)
              acc[mg][ng][i][j] += av[mg][i]*bv[ng][j];
    }
  }
  int b = m0 / LEN, l0 = m0 % LEN;
  #pragma unroll
  for(int ng=0;ng<2;ng++)
    #pragma unroll
    for(int j=0;j<4;j++){
      int n = n0 + ng*64 + tx*4 + j;
      #pragma unroll
      for(int mg=0;mg<2;mg++){
        float4 v = {acc[mg][ng][0][j],acc[mg][ng][1][j],acc[mg][ng][2][j],acc[mg][ng][3][j]};
        *(float4*)&out[((size_t)b*DIM + n)*LEN + l0 + mg*64 + ty*4] = v;
      }
    }
}

extern "C" void kernel_launch(void* const* d_in, const int* in_sizes, int n_in,
                              void* d_out, int out_size, void* d_ws, size_t ws_size,
                              hipStream_t stream) {
  const float* x    = (const float*)d_in[0];
  const float* lnw  = (const float*)d_in[1];
  const float* lnb  = (const float*)d_in[2];
  const float* Win  = (const float*)d_in[3];
  const float* cw   = (const float*)d_in[4];
  const float* cb   = (const float*)d_in[5];
  const float* Wxp  = (const float*)d_in[6];
  const float* Wdt  = (const float*)d_in[7];
  const float* bdt  = (const float*)d_in[8];
  const float* Alog = (const float*)d_in[9];
  const float* Dp   = (const float*)d_in[10];
  const float* Wout = (const float*)d_in[11];
  float* out = (float*)d_out;
  float* ws  = (float*)d_ws;

  // workspace layout (float slots), total ~148.1 MiB:
  float*    mu   = ws;                         //    16,384
  float*    rs   = mu + 16384;                 //    16,384
  float*    xinD = rs + 16384;                 // 16,777,216  xin -> delta -> y (fp32)
  ushort_t* sz   = (ushort_t*)(xinD + 16777216); // 16,777,216 bf16 (8,388,608 float slots)
  ushort_t* u    = (ushort_t*)((float*)sz + 8388608); // bf16, 8,388,608 float slots
  float*    dbl  = (float*)u + 8388608;        //  1,048,576
  float*    P    = dbl + 1048576;              //  2,097,152
  float*    E    = P + 2097152;                //  2,097,152 (Hs in-place)

  hipLaunchKernelGGL(ln_stats_k,  dim3(256),      dim3(256), 0, stream, x, mu, rs);
  hipLaunchKernelGGL(gemm1_k,     dim3(16,128),   dim3(256), 0, stream, x, mu, rs, lnw, lnb, Win, xinD, sz);
  hipLaunchKernelGGL(conv_silu_k, dim3(65536),    dim3(256), 0, stream, xinD, cw, cb, u);
  hipLaunchKernelGGL(gemm2_k,     dim3(256),      dim3(256), 0, stream, u, Wxp, dbl);
  hipLaunchKernelGGL(gemm3_k,     dim3(16,256),   dim3(256), 0, stream, dbl, Wdt, bdt, xinD);
  hipLaunchKernelGGL(scanA_k,     dim3(512),      dim3(256), 0, stream, xinD, u, dbl, Alog, P, E);
  hipLaunchKernelGGL(scanB_k,     dim3(256),      dim3(256), 0, stream, P, E);
  hipLaunchKernelGGL(scanC_k,     dim3(512),      dim3(256), 0, stream, xinD, u, dbl, Alog, E, Dp, sz);
  hipLaunchKernelGGL(gemm4_k,     dim3(4,128),    dim3(256), 0, stream, xinD, Wout, out);
}

// Round 3
// 626.556 us; speedup vs baseline: 1.7818x; 1.7818x over previous
//
#include <hip/hip_runtime.h>
#include <math.h>

#define Bsz 4
#define DIM 512
#define LEN 4096
#define DST 16
#define DIN 1024
#define NCH 32    // chunks over L
#define CHL 128   // chunk length

typedef unsigned short ushort_t;
typedef unsigned int uint_t;
typedef __attribute__((ext_vector_type(8))) short short8;   // 8 bf16 (4 VGPRs)
typedef __attribute__((ext_vector_type(4))) float f32x4;

__device__ __forceinline__ float sigmoidf_(float x){ return 1.0f/(1.0f+__expf(-x)); }
__device__ __forceinline__ float softplusf_(float x){ return x > 20.0f ? x : log1pf(__expf(x)); }
__device__ __forceinline__ float bf2f(ushort_t u){ return __uint_as_float(((uint_t)u) << 16); }
__device__ __forceinline__ ushort_t f2bf(float f){
  uint_t x = __float_as_uint(f);
  uint_t r = (x + 0x7FFFu + ((x >> 16) & 1u)) >> 16;
  return (ushort_t)r;
}
__device__ __forceinline__ void gl2lds16(const void* g, void* l){
  __builtin_amdgcn_global_load_lds((const __attribute__((address_space(1))) void*)g,
                                   (__attribute__((address_space(3))) void*)l, 16, 0, 0);
}

// ---------------- LayerNorm stats ----------------
__global__ __launch_bounds__(256) void ln_stats_k(const float* __restrict__ x,
                                                  float* __restrict__ mu, float* __restrict__ rs){
  int bid = blockIdx.x;
  int b = bid >> 6;
  int lg = bid & 63;
  int lane = threadIdx.x & 63;
  int g = threadIdx.x >> 6;
  int l = lg*64 + lane;
  const float* xb = x + (size_t)b*DIM*LEN + l;
  float s = 0.f, sq = 0.f;
  for(int d = g*128; d < g*128 + 128; ++d){
    float v = xb[(size_t)d*LEN];
    s += v; sq += v*v;
  }
  __shared__ float rsum[4][64], rsq[4][64];
  rsum[g][lane] = s; rsq[g][lane] = sq;
  __syncthreads();
  if(threadIdx.x < 64){
    float ts = 0.f, tq = 0.f;
    for(int gg=0; gg<4; ++gg){ ts += rsum[gg][lane]; tq += rsq[gg][lane]; }
    float m = ts * (1.0f/DIM);
    float var = tq * (1.0f/DIM) - m*m;
    mu[b*LEN + l] = m;
    rs[b*LEN + l] = rsqrtf(var + 1e-5f);
  }
}

// ---------------- weights -> bf16 ----------------
__global__ __launch_bounds__(256) void wcvt_k(const float* __restrict__ Win,
    const float* __restrict__ Wout, const float* __restrict__ Wxp,
    ushort_t* __restrict__ Winb, ushort_t* __restrict__ Woutb, ushort_t* __restrict__ Wxpb){
  int i = blockIdx.x*256 + threadIdx.x;   // 1,638,400 total
  if(i < 1048576) Winb[i] = f2bf(Win[i]);
  else if(i < 1572864) Woutb[i-1048576] = f2bf(Wout[i-1048576]);
  else if(i < 1638400) Wxpb[i-1572864] = f2bf(Wxp[i-1572864]);
}

// ---------------- LN apply + transpose -> xnT bf16 [B*L][512] ----------------
__global__ __launch_bounds__(256) void xnt_k(const float* __restrict__ x,
    const float* __restrict__ mu, const float* __restrict__ rs,
    const float* __restrict__ lnw, const float* __restrict__ lnb, ushort_t* __restrict__ xnT){
  __shared__ ushort_t t[64][72];
  int bid = blockIdx.x;              // 4 * 8 * 64 = 2048
  int lt = bid & 63;
  int dt_ = (bid >> 6) & 7;
  int b = bid >> 9;
  int l0 = lt*64, d0 = dt_*64;
  int ll = threadIdx.x & 63;
  int dq = threadIdx.x >> 6;
  float mul_ = mu[b*LEN + l0 + ll], rsl = rs[b*LEN + l0 + ll];
  const float* xb = x + (size_t)b*DIM*LEN;
  #pragma unroll
  for(int i=0;i<16;i++){
    int d = d0 + dq*16 + i;
    float v = xb[(size_t)d*LEN + l0 + ll];
    t[ll][dq*16 + i] = f2bf((v - mul_)*rsl*lnw[d] + lnb[d]);
  }
  __syncthreads();
  int lr = threadIdx.x >> 2, seg = threadIdx.x & 3;
  ushort_t* dst = &xnT[(size_t)(b*LEN + l0 + lr)*DIM + d0 + seg*16];
  #pragma unroll
  for(int k=0;k<4;k++){
    ushort4 v = *(const ushort4*)&t[lr][seg*16 + k*4];
    *(ushort4*)&dst[k*4] = v;
  }
}

// ---------------- GEMM1 MFMA: xnT[16384][512] x Winb[2048][512] -> xin fp32 / sz bf16 ----------------
__global__ __launch_bounds__(256) void gemm1_mfma(const ushort_t* __restrict__ A,
    const ushort_t* __restrict__ Bw, float* __restrict__ xin, ushort_t* __restrict__ sz){
  __shared__ __align__(16) ushort_t As[128*64];
  __shared__ __align__(16) ushort_t Bs[128*64];
  int tid = threadIdx.x;
  int wave = tid >> 6, lane = tid & 63;
  int n0 = blockIdx.x * 128;
  int m0 = blockIdx.y * 128;
  int wm = (wave >> 1) * 64, wn = (wave & 1) * 64;
  int lm = lane & 15;
  int lk = lane >> 4;
  f32x4 zero4 = {0.f,0.f,0.f,0.f};
  f32x4 acc[4][4];
  #pragma unroll
  for(int i=0;i<4;i++)
    #pragma unroll
    for(int j=0;j<4;j++) acc[i][j] = zero4;
  for(int k0=0; k0<512; k0+=64){
    __syncthreads();
    #pragma unroll
    for(int i=0;i<4;i++){
      int c = i*256 + tid;
      int r = c >> 3, kc = c & 7;
      gl2lds16(&A [(size_t)(m0 + r)*512 + k0 + kc*8], &As[c*8]);
      gl2lds16(&Bw[(size_t)(n0 + r)*512 + k0 + kc*8], &Bs[c*8]);
    }
    __syncthreads();
    #pragma unroll
    for(int kk=0; kk<64; kk+=32){
      short8 af[4], bf[4];
      #pragma unroll
      for(int i=0;i<4;i++){
        af[i] = *(const short8*)&As[(wm + i*16 + lm)*64 + kk + lk*8];
        bf[i] = *(const short8*)&Bs[(wn + i*16 + lm)*64 + kk + lk*8];
      }
      #pragma unroll
      for(int i=0;i<4;i++)
        #pragma unroll
        for(int j=0;j<4;j++)
          acc[i][j] = __builtin_amdgcn_mfma_f32_16x16x32_bf16(af[i], bf[j], acc[i][j], 0, 0, 0);
    }
  }
  bool is_z = (n0 >= 1024);
  #pragma unroll
  for(int i=0;i<4;i++)
    #pragma unroll
    for(int j=0;j<4;j++)
      #pragma unroll
      for(int r=0;r<4;r++){
        int m = m0 + wm + i*16 + lk*4 + r;
        int n = n0 + wn + j*16 + lm;
        float v = acc[i][j][r];
        if(!is_z) xin[(size_t)m*DIN + n] = v;
        else      sz[(size_t)m*DIN + (n-1024)] = f2bf(v * sigmoidf_(v));
      }
}

// ---------------- conv1d + SiLU -> u bf16 ----------------
__global__ __launch_bounds__(256) void conv_silu_k(const float* __restrict__ xin,
    const float* __restrict__ cw, const float* __restrict__ cb, ushort_t* __restrict__ u){
  int idx = blockIdx.x*256 + threadIdx.x;
  int d = idx & 1023;
  int r = idx >> 10;
  int l = r & 4095;
  int b = r >> 12;
  float acc = cb[d];
  const float* base = xin + (size_t)b*LEN*DIN + d;
  #pragma unroll
  for(int j=0;j<4;j++){
    int ls = l - 3 + j;
    if(ls >= 0) acc += base[(size_t)ls*DIN] * cw[d*4+j];
  }
  u[idx] = f2bf(acc * sigmoidf_(acc));
}

// ---------------- GEMM2 MFMA: u[16384][1024] x Wxpb[64][1024] -> dbl fp32 [16384][64] ----------------
__global__ __launch_bounds__(256) void gemm2_mfma(const ushort_t* __restrict__ A,
    const ushort_t* __restrict__ Bw, float* __restrict__ dbl){
  __shared__ __align__(16) ushort_t As[128*64];
  __shared__ __align__(16) ushort_t Bs[64*64];
  int tid = threadIdx.x;
  int wave = tid >> 6, lane = tid & 63;
  int m0 = blockIdx.x * 128;
  int wm = (wave >> 1) * 64, wn = (wave & 1) * 32;
  int lm = lane & 15;
  int lk = lane >> 4;
  f32x4 zero4 = {0.f,0.f,0.f,0.f};
  f32x4 acc[4][2];
  #pragma unroll
  for(int i=0;i<4;i++){ acc[i][0] = zero4; acc[i][1] = zero4; }
  for(int k0=0; k0<1024; k0+=64){
    __syncthreads();
    #pragma unroll
    for(int i=0;i<4;i++){
      int c = i*256 + tid;
      int r = c >> 3, kc = c & 7;
      gl2lds16(&A[(size_t)(m0 + r)*1024 + k0 + kc*8], &As[c*8]);
    }
    #pragma unroll
    for(int i=0;i<2;i++){
      int c = i*256 + tid;
      int r = c >> 3, kc = c & 7;
      gl2lds16(&Bw[(size_t)r*1024 + k0 + kc*8], &Bs[c*8]);
    }
    __syncthreads();
    #pragma unroll
    for(int kk=0; kk<64; kk+=32){
      short8 af[4], bf[2];
      #pragma unroll
      for(int i=0;i<4;i++) af[i] = *(const short8*)&As[(wm + i*16 + lm)*64 + kk + lk*8];
      #pragma unroll
      for(int j=0;j<2;j++) bf[j] = *(const short8*)&Bs[(wn + j*16 + lm)*64 + kk + lk*8];
      #pragma unroll
      for(int i=0;i<4;i++)
        #pragma unroll
        for(int j=0;j<2;j++)
          acc[i][j] = __builtin_amdgcn_mfma_f32_16x16x32_bf16(af[i], bf[j], acc[i][j], 0, 0, 0);
    }
  }
  #pragma unroll
  for(int i=0;i<4;i++)
    #pragma unroll
    for(int j=0;j<2;j++)
      #pragma unroll
      for(int r=0;r<4;r++){
        int m = m0 + wm + i*16 + lk*4 + r;
        int n = wn + j*16 + lm;
        dbl[(size_t)m*64 + n] = acc[i][j][r];
      }
}

// ---------------- scan phase A (delta fused): per-chunk (prod a, local end state) ----------------
__global__ __launch_bounds__(256) void scanA_k(const ushort_t* __restrict__ u,
    const float* __restrict__ dbl, const float* __restrict__ Wdt, const float* __restrict__ bdt,
    const float* __restrict__ Alog, float* __restrict__ P, float* __restrict__ E){
  __shared__ __align__(16) float dch[CHL*64];
  int bid = blockIdx.x;            // Bsz*4*NCH = 512
  int c = bid & (NCH-1);
  int dblk = (bid >> 5) & 3;
  int b = bid >> 7;
  int d = dblk*256 + threadIdx.x;
  const f32x4* src = (const f32x4*)(dbl + ((size_t)b*LEN + c*CHL)*64);
  f32x4* dst4 = (f32x4*)dch;
  for(int i=threadIdx.x; i<CHL*16; i+=256) dst4[i] = src[i];
  float w[32];
  #pragma unroll
  for(int k=0;k<32;k+=4){
    float4 t4 = *(const float4*)&Wdt[d*32+k];
    w[k]=t4.x; w[k+1]=t4.y; w[k+2]=t4.z; w[k+3]=t4.w;
  }
  float bd = bdt[d];
  float nA[DST], Ps[DST], Es[DST];
  #pragma unroll
  for(int s=0;s<DST;s++){ nA[s] = -__expf(Alog[d*DST+s]); Ps[s]=1.f; Es[s]=0.f; }
  __syncthreads();
  const ushort_t* uu = u + ((size_t)b*LEN + c*CHL)*DIN + d;
  for(int t=0;t<CHL;++t){
    const float* row = dch + t*64;
    float dtv = bd;
    #pragma unroll
    for(int k=0;k<32;k+=4){
      float4 q = *(const float4*)&row[k];
      dtv += q.x*w[k] + q.y*w[k+1] + q.z*w[k+2] + q.w*w[k+3];
    }
    float dv = softplusf_(dtv);
    float uv = bf2f(uu[(size_t)t*DIN]);
    float du = dv*uv;
    #pragma unroll
    for(int s=0;s<DST;s++){
      float a = __expf(dv * nA[s]);
      Ps[s] *= a;
      Es[s] = a*Es[s] + du*row[32+s];
    }
  }
  size_t o = (size_t)(b*NCH + c)*DST*DIN + d;
  #pragma unroll
  for(int s=0;s<DST;s++){ P[o + (size_t)s*DIN] = Ps[s]; E[o + (size_t)s*DIN] = Es[s]; }
}

// ---------------- scan phase B: combine chunk boundaries; Hs in-place over E ----------------
__global__ __launch_bounds__(256) void scanB_k(const float* __restrict__ P, float* __restrict__ E){
  int g = blockIdx.x*256 + threadIdx.x;
  int d = g & 1023;
  int s = (g >> 10) & 15;
  int b = g >> 14;
  float h = 0.f;
  for(int c=0;c<NCH;c++){
    size_t o = (size_t)((b*NCH + c)*DST + s)*DIN + d;
    float p = P[o], e = E[o];
    E[o] = h;
    h = p*h + e;
  }
}

// ---------------- scan phase C (delta fused): replay, y=(scan+u*D)*sz, write y bf16 over u ----------------
__global__ __launch_bounds__(256) void scanC_k(ushort_t* __restrict__ u,
    const float* __restrict__ dbl, const float* __restrict__ Wdt, const float* __restrict__ bdt,
    const float* __restrict__ Alog, const float* __restrict__ Hs, const float* __restrict__ Dp,
    const ushort_t* __restrict__ sz){
  __shared__ __align__(16) float dch[CHL*64];
  int bid = blockIdx.x;
  int c = bid & (NCH-1);
  int dblk = (bid >> 5) & 3;
  int b = bid >> 7;
  int d = dblk*256 + threadIdx.x;
  const f32x4* src = (const f32x4*)(dbl + ((size_t)b*LEN + c*CHL)*64);
  f32x4* dst4 = (f32x4*)dch;
  for(int i=threadIdx.x; i<CHL*16; i+=256) dst4[i] = src[i];
  float w[32];
  #pragma unroll
  for(int k=0;k<32;k+=4){
    float4 t4 = *(const float4*)&Wdt[d*32+k];
    w[k]=t4.x; w[k+1]=t4.y; w[k+2]=t4.z; w[k+3]=t4.w;
  }
  float bd = bdt[d];
  float nA[DST], h[DST];
  size_t ho = (size_t)(b*NCH + c)*DST*DIN + d;
  #pragma unroll
  for(int s=0;s<DST;s++){ nA[s] = -__expf(Alog[d*DST+s]); h[s] = Hs[ho + (size_t)s*DIN]; }
  float Dv = Dp[d];
  __syncthreads();
  ushort_t* uu = u + ((size_t)b*LEN + c*CHL)*DIN + d;
  const ushort_t* zz = sz + ((size_t)b*LEN + c*CHL)*DIN + d;
  for(int t=0;t<CHL;++t){
    const float* row = dch + t*64;
    float dtv = bd;
    #pragma unroll
    for(int k=0;k<32;k+=4){
      float4 q = *(const float4*)&row[k];
      dtv += q.x*w[k] + q.y*w[k+1] + q.z*w[k+2] + q.w*w[k+3];
    }
    float dv = softplusf_(dtv);
    float uv = bf2f(uu[(size_t)t*DIN]);
    float du = dv*uv;
    float y = 0.f;
    #pragma unroll
    for(int s=0;s<DST;s++){
      float a = __expf(dv*nA[s]);
      h[s] = a*h[s] + du*row[32+s];
      y += h[s]*row[48+s];
    }
    y += uv*Dv;
    y *= bf2f(zz[(size_t)t*DIN]);
    uu[(size_t)t*DIN] = f2bf(y);
  }
}

// ---------------- GEMM4 MFMA: y[16384][1024] x Woutb[512][1024] -> out[b][n][l] ----------------
__global__ __launch_bounds__(256) void gemm4_mfma(const ushort_t* __restrict__ A,
    const ushort_t* __restrict__ Bw, float* __restrict__ out){
  __shared__ __align__(16) ushort_t smem[2*128*64];   // As | Bs ; epilogue reuses as float
  ushort_t* As = smem;
  ushort_t* Bs = smem + 128*64;
  int tid = threadIdx.x;
  int wave = tid >> 6, lane = tid & 63;
  int n0 = blockIdx.x * 128;       // N=512 -> 4
  int m0 = blockIdx.y * 128;
  int wm = (wave >> 1) * 64, wn = (wave & 1) * 64;
  int lm = lane & 15;
  int lk = lane >> 4;
  f32x4 zero4 = {0.f,0.f,0.f,0.f};
  f32x4 acc[4][4];
  #pragma unroll
  for(int i=0;i<4;i++)
    #pragma unroll
    for(int j=0;j<4;j++) acc[i][j] = zero4;
  for(int k0=0; k0<1024; k0+=64){
    __syncthreads();
    #pragma unroll
    for(int i=0;i<4;i++){
      int c = i*256 + tid;
      int r = c >> 3, kc = c & 7;
      gl2lds16(&A [(size_t)(m0 + r)*1024 + k0 + kc*8], &As[c*8]);
      gl2lds16(&Bw[(size_t)(n0 + r)*1024 + k0 + kc*8], &Bs[c*8]);
    }
    __syncthreads();
    #pragma unroll
    for(int kk=0; kk<64; kk+=32){
      short8 af[4], bf[4];
      #pragma unroll
      for(int i=0;i<4;i++){
        af[i] = *(const short8*)&As[(wm + i*16 + lm)*64 + kk + lk*8];
        bf[i] = *(const short8*)&Bs[(wn + i*16 + lm)*64 + kk + lk*8];
      }
      #pragma unroll
      for(int i=0;i<4;i++)
        #pragma unroll
        for(int j=0;j<4;j++)
          acc[i][j] = __builtin_amdgcn_mfma_f32_16x16x32_bf16(af[i], bf[j], acc[i][j], 0, 0, 0);
    }
  }
  // epilogue: LDS transpose, 32-n groups, coalesced float4 stores along l(=m)
  float* T = (float*)smem;               // [32][132] fp32 = 16.9KB <= 32KB
  int b = m0 >> 12, l0 = m0 & 4095;
  for(int g=0; g<4; ++g){
    __syncthreads();
    if((g >> 1) == (wave & 1)){
      int jg = g & 1;
      #pragma unroll
      for(int j2=0;j2<2;j2++){
        int j = jg*2 + j2;
        #pragma unroll
        for(int i=0;i<4;i++)
          #pragma unroll
          for(int r=0;r<4;r++){
            int ml = wm + i*16 + lk*4 + r;
            int nl = wn + j*16 + lm - g*32;
            T[nl*132 + ml] = acc[i][j][r];
          }
      }
    }
    __syncthreads();
    int nl = tid >> 3, seg = tid & 7;
    float* dst = &out[((size_t)b*DIM + n0 + g*32 + nl)*LEN + l0 + seg*16];
    #pragma unroll
    for(int k=0;k<4;k++){
      float4 v = *(const float4*)&T[nl*132 + seg*16 + k*4];
      *(float4*)&dst[k*4] = v;
    }
  }
}

extern "C" void kernel_launch(void* const* d_in, const int* in_sizes, int n_in,
                              void* d_out, int out_size, void* d_ws, size_t ws_size,
                              hipStream_t stream) {
  const float* x    = (const float*)d_in[0];
  const float* lnw  = (const float*)d_in[1];
  const float* lnb  = (const float*)d_in[2];
  const float* Win  = (const float*)d_in[3];
  const float* cw   = (const float*)d_in[4];
  const float* cb   = (const float*)d_in[5];
  const float* Wxp  = (const float*)d_in[6];
  const float* Wdt  = (const float*)d_in[7];
  const float* bdt  = (const float*)d_in[8];
  const float* Alog = (const float*)d_in[9];
  const float* Dp   = (const float*)d_in[10];
  const float* Wout = (const float*)d_in[11];
  float* out = (float*)d_out;
  float* ws  = (float*)d_ws;

  // workspace layout (float-slot offsets), total 147.3 MiB
  float*    mu   = ws;                         // 16384
  float*    rs   = ws + 16384;                 // 16384
  float*    xin  = ws + 32768;                 // 16,777,216 fp32 (dead after conv)
  float*    P    = xin;                        // alias: 2,097,152
  float*    E    = xin + 2097152;              // alias: 2,097,152 (Hs in-place)
  ushort_t* sz   = (ushort_t*)(ws + 32768 + 16777216);            // bf16 16,777,216
  ushort_t* u    = (ushort_t*)(ws + 32768 + 16777216 + 8388608);  // bf16 16,777,216 (y overwrites)
  ushort_t* xnT  = (ushort_t*)(ws + 32768 + 16777216 + 16777216); // bf16 8,388,608
  float*    dbl  = (float*)xnT;                // alias after gemm1: 1,048,576 fp32
  ushort_t* Winb = (ushort_t*)(ws + 32768 + 16777216 + 16777216 + 4194304);
  ushort_t* Woutb= Winb + 1048576;
  ushort_t* Wxpb = Woutb + 524288;

  hipLaunchKernelGGL(ln_stats_k, dim3(256),     dim3(256), 0, stream, x, mu, rs);
  hipLaunchKernelGGL(wcvt_k,     dim3(6400),    dim3(256), 0, stream, Win, Wout, Wxp, Winb, Woutb, Wxpb);
  hipLaunchKernelGGL(xnt_k,      dim3(2048),    dim3(256), 0, stream, x, mu, rs, lnw, lnb, xnT);
  hipLaunchKernelGGL(gemm1_mfma, dim3(16,128),  dim3(256), 0, stream, xnT, Winb, xin, sz);
  hipLaunchKernelGGL(conv_silu_k,dim3(65536),   dim3(256), 0, stream, xin, cw, cb, u);
  hipLaunchKernelGGL(gemm2_mfma, dim3(128),     dim3(256), 0, stream, u, Wxpb, dbl);
  hipLaunchKernelGGL(scanA_k,    dim3(512),     dim3(256), 0, stream, u, dbl, Wdt, bdt, Alog, P, E);
  hipLaunchKernelGGL(scanB_k,    dim3(256),     dim3(256), 0, stream, P, E);
  hipLaunchKernelGGL(scanC_k,    dim3(512),     dim3(256), 0, stream, u, dbl, Wdt, bdt, Alog, E, Dp, sz);
  hipLaunchKernelGGL(gemm4_mfma, dim3(4,128),   dim3(256), 0, stream, u, Woutb, out);
}

// Round 4
// 528.329 us; speedup vs baseline: 2.1131x; 1.1859x over previous
//
#include <hip/hip_runtime.h>
#include <math.h>

#define Bsz 4
#define DIM 512
#define LEN 4096
#define DST 16
#define DIN 1024
#define NCH 32    // chunks over L
#define CHL 128   // chunk length

typedef unsigned short ushort_t;
typedef unsigned int uint_t;
typedef __attribute__((ext_vector_type(8))) short short8;   // 8 bf16 (4 VGPRs)
typedef __attribute__((ext_vector_type(4))) float f32x4;

__device__ __forceinline__ float sigmoidf_(float x){ return 1.0f/(1.0f+__expf(-x)); }
__device__ __forceinline__ float bf2f(ushort_t u){ return __uint_as_float(((uint_t)u) << 16); }
__device__ __forceinline__ ushort_t f2bf(float f){
  uint_t x = __float_as_uint(f);
  uint_t r = (x + 0x7FFFu + ((x >> 16) & 1u)) >> 16;
  return (ushort_t)r;
}
__device__ __forceinline__ void gl2lds16(const void* g, void* l){
  __builtin_amdgcn_global_load_lds((const __attribute__((address_space(1))) void*)g,
                                   (__attribute__((address_space(3))) void*)l, 16, 0, 0);
}

// ---------------- LayerNorm stats ----------------
__global__ __launch_bounds__(256) void ln_stats_k(const float* __restrict__ x,
                                                  float* __restrict__ mu, float* __restrict__ rs){
  int bid = blockIdx.x;
  int b = bid >> 6;
  int lg = bid & 63;
  int lane = threadIdx.x & 63;
  int g = threadIdx.x >> 6;
  int l = lg*64 + lane;
  const float* xb = x + (size_t)b*DIM*LEN + l;
  float s = 0.f, sq = 0.f;
  for(int d = g*128; d < g*128 + 128; ++d){
    float v = xb[(size_t)d*LEN];
    s += v; sq += v*v;
  }
  __shared__ float rsum[4][64], rsq[4][64];
  rsum[g][lane] = s; rsq[g][lane] = sq;
  __syncthreads();
  if(threadIdx.x < 64){
    float ts = 0.f, tq = 0.f;
    for(int gg=0; gg<4; ++gg){ ts += rsum[gg][lane]; tq += rsq[gg][lane]; }
    float m = ts * (1.0f/DIM);
    float var = tq * (1.0f/DIM) - m*m;
    mu[b*LEN + l] = m;
    rs[b*LEN + l] = rsqrtf(var + 1e-5f);
  }
}

// ---------------- weights -> bf16 ----------------
__global__ __launch_bounds__(256) void wcvt_k(const float* __restrict__ Win,
    const float* __restrict__ Wout, const float* __restrict__ Wxp,
    ushort_t* __restrict__ Winb, ushort_t* __restrict__ Woutb, ushort_t* __restrict__ Wxpb){
  int i = blockIdx.x*256 + threadIdx.x;   // 1,638,400 total
  if(i < 1048576) Winb[i] = f2bf(Win[i]);
  else if(i < 1572864) Woutb[i-1048576] = f2bf(Wout[i-1048576]);
  else if(i < 1638400) Wxpb[i-1572864] = f2bf(Wxp[i-1572864]);
}

// ---------------- LN apply + transpose -> xnT bf16 [B*L][512] ----------------
__global__ __launch_bounds__(256) void xnt_k(const float* __restrict__ x,
    const float* __restrict__ mu, const float* __restrict__ rs,
    const float* __restrict__ lnw, const float* __restrict__ lnb, ushort_t* __restrict__ xnT){
  __shared__ ushort_t t[64][72];
  int bid = blockIdx.x;              // 4 * 8 * 64 = 2048
  int lt = bid & 63;
  int dt_ = (bid >> 6) & 7;
  int b = bid >> 9;
  int l0 = lt*64, d0 = dt_*64;
  int ll = threadIdx.x & 63;
  int dq = threadIdx.x >> 6;
  float mul_ = mu[b*LEN + l0 + ll], rsl = rs[b*LEN + l0 + ll];
  const float* xb = x + (size_t)b*DIM*LEN;
  #pragma unroll
  for(int i=0;i<16;i++){
    int d = d0 + dq*16 + i;
    float v = xb[(size_t)d*LEN + l0 + ll];
    t[ll][dq*16 + i] = f2bf((v - mul_)*rsl*lnw[d] + lnb[d]);
  }
  __syncthreads();
  int lr = threadIdx.x >> 2, seg = threadIdx.x & 3;
  ushort_t* dst = &xnT[(size_t)(b*LEN + l0 + lr)*DIM + d0 + seg*16];
  #pragma unroll
  for(int k=0;k<4;k++){
    ushort4 v = *(const ushort4*)&t[lr][seg*16 + k*4];
    *(ushort4*)&dst[k*4] = v;
  }
}

// ---------------- GEMM1 MFMA: xnT[16384][512] x Winb[2048][512] -> xin fp32 / sz bf16 ----------------
__global__ __launch_bounds__(256) void gemm1_mfma(const ushort_t* __restrict__ A,
    const ushort_t* __restrict__ Bw, float* __restrict__ xin, ushort_t* __restrict__ sz){
  __shared__ __align__(16) ushort_t As[128*64];
  __shared__ __align__(16) ushort_t Bs[128*64];
  int tid = threadIdx.x;
  int wave = tid >> 6, lane = tid & 63;
  int n0 = blockIdx.x * 128;
  int m0 = blockIdx.y * 128;
  int wm = (wave >> 1) * 64, wn = (wave & 1) * 64;
  int lm = lane & 15;
  int lk = lane >> 4;
  f32x4 zero4 = {0.f,0.f,0.f,0.f};
  f32x4 acc[4][4];
  #pragma unroll
  for(int i=0;i<4;i++)
    #pragma unroll
    for(int j=0;j<4;j++) acc[i][j] = zero4;
  for(int k0=0; k0<512; k0+=64){
    __syncthreads();
    #pragma unroll
    for(int i=0;i<4;i++){
      int c = i*256 + tid;
      int r = c >> 3, kc = c & 7;
      gl2lds16(&A [(size_t)(m0 + r)*512 + k0 + kc*8], &As[c*8]);
      gl2lds16(&Bw[(size_t)(n0 + r)*512 + k0 + kc*8], &Bs[c*8]);
    }
    __syncthreads();
    #pragma unroll
    for(int kk=0; kk<64; kk+=32){
      short8 af[4], bf[4];
      #pragma unroll
      for(int i=0;i<4;i++){
        af[i] = *(const short8*)&As[(wm + i*16 + lm)*64 + kk + lk*8];
        bf[i] = *(const short8*)&Bs[(wn + i*16 + lm)*64 + kk + lk*8];
      }
      #pragma unroll
      for(int i=0;i<4;i++)
        #pragma unroll
        for(int j=0;j<4;j++)
          acc[i][j] = __builtin_amdgcn_mfma_f32_16x16x32_bf16(af[i], bf[j], acc[i][j], 0, 0, 0);
    }
  }
  bool is_z = (n0 >= 1024);
  #pragma unroll
  for(int i=0;i<4;i++)
    #pragma unroll
    for(int j=0;j<4;j++)
      #pragma unroll
      for(int r=0;r<4;r++){
        int m = m0 + wm + i*16 + lk*4 + r;
        int n = n0 + wn + j*16 + lm;
        float v = acc[i][j][r];
        if(!is_z) xin[(size_t)m*DIN + n] = v;
        else      sz[(size_t)m*DIN + (n-1024)] = f2bf(v * sigmoidf_(v));
      }
}

// ---------------- conv1d + SiLU -> u bf16 ----------------
__global__ __launch_bounds__(256) void conv_silu_k(const float* __restrict__ xin,
    const float* __restrict__ cw, const float* __restrict__ cb, ushort_t* __restrict__ u){
  int idx = blockIdx.x*256 + threadIdx.x;
  int d = idx & 1023;
  int r = idx >> 10;
  int l = r & 4095;
  int b = r >> 12;
  float acc = cb[d];
  const float* base = xin + (size_t)b*LEN*DIN + d;
  #pragma unroll
  for(int j=0;j<4;j++){
    int ls = l - 3 + j;
    if(ls >= 0) acc += base[(size_t)ls*DIN] * cw[d*4+j];
  }
  u[idx] = f2bf(acc * sigmoidf_(acc));
}

// ---------------- GEMM2 MFMA: u[16384][1024] x Wxpb[64][1024] -> dbl fp32 [16384][64] ----------------
__global__ __launch_bounds__(256) void gemm2_mfma(const ushort_t* __restrict__ A,
    const ushort_t* __restrict__ Bw, float* __restrict__ dbl){
  __shared__ __align__(16) ushort_t As[128*64];
  __shared__ __align__(16) ushort_t Bs[64*64];
  int tid = threadIdx.x;
  int wave = tid >> 6, lane = tid & 63;
  int m0 = blockIdx.x * 128;
  int wm = (wave >> 1) * 64, wn = (wave & 1) * 32;
  int lm = lane & 15;
  int lk = lane >> 4;
  f32x4 zero4 = {0.f,0.f,0.f,0.f};
  f32x4 acc[4][2];
  #pragma unroll
  for(int i=0;i<4;i++){ acc[i][0] = zero4; acc[i][1] = zero4; }
  for(int k0=0; k0<1024; k0+=64){
    __syncthreads();
    #pragma unroll
    for(int i=0;i<4;i++){
      int c = i*256 + tid;
      int r = c >> 3, kc = c & 7;
      gl2lds16(&A[(size_t)(m0 + r)*1024 + k0 + kc*8], &As[c*8]);
    }
    #pragma unroll
    for(int i=0;i<2;i++){
      int c = i*256 + tid;
      int r = c >> 3, kc = c & 7;
      gl2lds16(&Bw[(size_t)r*1024 + k0 + kc*8], &Bs[c*8]);
    }
    __syncthreads();
    #pragma unroll
    for(int kk=0; kk<64; kk+=32){
      short8 af[4], bf[2];
      #pragma unroll
      for(int i=0;i<4;i++) af[i] = *(const short8*)&As[(wm + i*16 + lm)*64 + kk + lk*8];
      #pragma unroll
      for(int j=0;j<2;j++) bf[j] = *(const short8*)&Bs[(wn + j*16 + lm)*64 + kk + lk*8];
      #pragma unroll
      for(int i=0;i<4;i++)
        #pragma unroll
        for(int j=0;j<2;j++)
          acc[i][j] = __builtin_amdgcn_mfma_f32_16x16x32_bf16(af[i], bf[j], acc[i][j], 0, 0, 0);
    }
  }
  #pragma unroll
  for(int i=0;i<4;i++)
    #pragma unroll
    for(int j=0;j<2;j++)
      #pragma unroll
      for(int r=0;r<4;r++){
        int m = m0 + wm + i*16 + lk*4 + r;
        int n = wn + j*16 + lm;
        dbl[(size_t)m*64 + n] = acc[i][j][r];
      }
}

// ---------------- scan phase A: delta (stored hi+lo bf16), telescoped P, chunk end-state ----------------
__global__ __launch_bounds__(256,2) void scanA_k(const ushort_t* __restrict__ u,
    const float* __restrict__ dbl, const float* __restrict__ Wdt, const float* __restrict__ bdt,
    const float* __restrict__ Alog, float* __restrict__ P, float* __restrict__ E,
    ushort_t* __restrict__ dhi, ushort_t* __restrict__ dlo){
  __shared__ __align__(16) float dch[CHL*64];
  int bid = blockIdx.x;            // Bsz*4*NCH = 512
  int c = bid & (NCH-1);
  int dblk = (bid >> 5) & 3;
  int b = bid >> 7;
  int d = dblk*256 + threadIdx.x;
  const f32x4* src = (const f32x4*)(dbl + ((size_t)b*LEN + c*CHL)*64);
  f32x4* dst4 = (f32x4*)dch;
  for(int i=threadIdx.x; i<CHL*16; i+=256) dst4[i] = src[i];
  float w[32];
  #pragma unroll
  for(int k=0;k<32;k+=4){
    float4 t4 = *(const float4*)&Wdt[d*32+k];
    w[k]=t4.x; w[k+1]=t4.y; w[k+2]=t4.z; w[k+3]=t4.w;
  }
  float bd = bdt[d];
  float nA[DST];
  bool fast = true;
  #pragma unroll
  for(int s=0;s<DST;s++){
    nA[s] = -__expf(Alog[d*DST+s]);
    fast = fast && (nA[s] == -(float)(s+1));
  }
  float Es[DST];
  #pragma unroll
  for(int s=0;s<DST;s++) Es[s] = 0.f;
  float cumD = 0.f;
  __syncthreads();
  const ushort_t* uu = u + ((size_t)b*LEN + c*CHL)*DIN + d;
  ushort_t* ph = dhi + ((size_t)b*LEN + c*CHL)*DIN + d;
  ushort_t* pl = dlo + ((size_t)b*LEN + c*CHL)*DIN + d;
  if(fast){
    for(int t=0;t<CHL;++t){
      const float* row = dch + t*64;
      float dtv = bd;
      #pragma unroll
      for(int k=0;k<32;k+=4){
        float4 q = *(const float4*)&row[k];
        dtv += q.x*w[k] + q.y*w[k+1] + q.z*w[k+2] + q.w*w[k+3];
      }
      float dv = dtv > 15.f ? dtv : __logf(1.f + __expf(dtv));
      ushort_t h16 = f2bf(dv);
      ph[(size_t)t*DIN] = h16;
      pl[(size_t)t*DIN] = f2bf(dv - bf2f(h16));
      float uv = bf2f(uu[(size_t)t*DIN]);
      float du = dv*uv;
      cumD += dv;
      float ea = __expf(-dv), a = 1.f;
      #pragma unroll
      for(int s=0;s<DST;s++){
        a *= ea;
        Es[s] = a*Es[s] + du*row[32+s];
      }
    }
  } else {
    for(int t=0;t<CHL;++t){
      const float* row = dch + t*64;
      float dtv = bd;
      #pragma unroll
      for(int k=0;k<32;k+=4){
        float4 q = *(const float4*)&row[k];
        dtv += q.x*w[k] + q.y*w[k+1] + q.z*w[k+2] + q.w*w[k+3];
      }
      float dv = dtv > 15.f ? dtv : __logf(1.f + __expf(dtv));
      ushort_t h16 = f2bf(dv);
      ph[(size_t)t*DIN] = h16;
      pl[(size_t)t*DIN] = f2bf(dv - bf2f(h16));
      float uv = bf2f(uu[(size_t)t*DIN]);
      float du = dv*uv;
      cumD += dv;
      #pragma unroll
      for(int s=0;s<DST;s++){
        float a = __expf(dv*nA[s]);
        Es[s] = a*Es[s] + du*row[32+s];
      }
    }
  }
  size_t o = (size_t)(b*NCH + c)*DST*DIN + d;
  #pragma unroll
  for(int s=0;s<DST;s++){
    P[o + (size_t)s*DIN] = __expf(cumD*nA[s]);
    E[o + (size_t)s*DIN] = Es[s];
  }
}

// ---------------- scan phase B: combine chunk boundaries; Hs in-place over E ----------------
__global__ __launch_bounds__(256) void scanB_k(const float* __restrict__ P, float* __restrict__ E){
  int g = blockIdx.x*256 + threadIdx.x;
  int d = g & 1023;
  int s = (g >> 10) & 15;
  int b = g >> 14;
  float h = 0.f;
  for(int c=0;c<NCH;c++){
    size_t o = (size_t)((b*NCH + c)*DST + s)*DIN + d;
    float p = P[o], e = E[o];
    E[o] = h;
    h = p*h + e;
  }
}

// ---------------- scan phase C: replay with loaded delta, y=(scan+u*D)*sz, y bf16 over u ----------------
__global__ __launch_bounds__(256,2) void scanC_k(ushort_t* __restrict__ u,
    const float* __restrict__ dbl, const float* __restrict__ Alog,
    const float* __restrict__ Hs, const float* __restrict__ Dp, const ushort_t* __restrict__ sz,
    const ushort_t* __restrict__ dhi, const ushort_t* __restrict__ dlo){
  __shared__ __align__(16) float dch[CHL*32];   // B,C cols only
  int bid = blockIdx.x;
  int c = bid & (NCH-1);
  int dblk = (bid >> 5) & 3;
  int b = bid >> 7;
  int d = dblk*256 + threadIdx.x;
  const f32x4* src = (const f32x4*)(dbl + ((size_t)b*LEN + c*CHL)*64);
  f32x4* dst4 = (f32x4*)dch;
  for(int i=threadIdx.x; i<CHL*8; i+=256){
    int t = i >> 3, q = i & 7;
    dst4[t*8 + q] = src[t*16 + 8 + q];
  }
  float nA[DST];
  bool fast = true;
  #pragma unroll
  for(int s=0;s<DST;s++){
    nA[s] = -__expf(Alog[d*DST+s]);
    fast = fast && (nA[s] == -(float)(s+1));
  }
  float h[DST];
  size_t ho = (size_t)(b*NCH + c)*DST*DIN + d;
  #pragma unroll
  for(int s=0;s<DST;s++) h[s] = Hs[ho + (size_t)s*DIN];
  float Dv = Dp[d];
  __syncthreads();
  ushort_t* uu = u + ((size_t)b*LEN + c*CHL)*DIN + d;
  const ushort_t* zz = sz + ((size_t)b*LEN + c*CHL)*DIN + d;
  const ushort_t* ph = dhi + ((size_t)b*LEN + c*CHL)*DIN + d;
  const ushort_t* pl = dlo + ((size_t)b*LEN + c*CHL)*DIN + d;
  if(fast){
    for(int t=0;t<CHL;++t){
      const float* row = dch + t*32;
      float dv = bf2f(ph[(size_t)t*DIN]) + bf2f(pl[(size_t)t*DIN]);
      float uv = bf2f(uu[(size_t)t*DIN]);
      float du = dv*uv;
      float ea = __expf(-dv), a = 1.f, y = 0.f;
      #pragma unroll
      for(int s=0;s<DST;s++){
        a *= ea;
        h[s] = a*h[s] + du*row[s];
        y += h[s]*row[16+s];
      }
      y += uv*Dv;
      y *= bf2f(zz[(size_t)t*DIN]);
      uu[(size_t)t*DIN] = f2bf(y);
    }
  } else {
    for(int t=0;t<CHL;++t){
      const float* row = dch + t*32;
      float dv = bf2f(ph[(size_t)t*DIN]) + bf2f(pl[(size_t)t*DIN]);
      float uv = bf2f(uu[(size_t)t*DIN]);
      float du = dv*uv;
      float y = 0.f;
      #pragma unroll
      for(int s=0;s<DST;s++){
        float a = __expf(dv*nA[s]);
        h[s] = a*h[s] + du*row[s];
        y += h[s]*row[16+s];
      }
      y += uv*Dv;
      y *= bf2f(zz[(size_t)t*DIN]);
      uu[(size_t)t*DIN] = f2bf(y);
    }
  }
}

// ---------------- GEMM4 MFMA: y[16384][1024] x Woutb[512][1024] -> out[b][n][l] ----------------
__global__ __launch_bounds__(256) void gemm4_mfma(const ushort_t* __restrict__ A,
    const ushort_t* __restrict__ Bw, float* __restrict__ out){
  __shared__ __align__(16) ushort_t smem[2*128*64];   // As | Bs ; epilogue reuses as float
  ushort_t* As = smem;
  ushort_t* Bs = smem + 128*64;
  int tid = threadIdx.x;
  int wave = tid >> 6, lane = tid & 63;
  int n0 = blockIdx.x * 128;       // N=512 -> 4
  int m0 = blockIdx.y * 128;
  int wm = (wave >> 1) * 64, wn = (wave & 1) * 64;
  int lm = lane & 15;
  int lk = lane >> 4;
  f32x4 zero4 = {0.f,0.f,0.f,0.f};
  f32x4 acc[4][4];
  #pragma unroll
  for(int i=0;i<4;i++)
    #pragma unroll
    for(int j=0;j<4;j++) acc[i][j] = zero4;
  for(int k0=0; k0<1024; k0+=64){
    __syncthreads();
    #pragma unroll
    for(int i=0;i<4;i++){
      int c = i*256 + tid;
      int r = c >> 3, kc = c & 7;
      gl2lds16(&A [(size_t)(m0 + r)*1024 + k0 + kc*8], &As[c*8]);
      gl2lds16(&Bw[(size_t)(n0 + r)*1024 + k0 + kc*8], &Bs[c*8]);
    }
    __syncthreads();
    #pragma unroll
    for(int kk=0; kk<64; kk+=32){
      short8 af[4], bf[4];
      #pragma unroll
      for(int i=0;i<4;i++){
        af[i] = *(const short8*)&As[(wm + i*16 + lm)*64 + kk + lk*8];
        bf[i] = *(const short8*)&Bs[(wn + i*16 + lm)*64 + kk + lk*8];
      }
      #pragma unroll
      for(int i=0;i<4;i++)
        #pragma unroll
        for(int j=0;j<4;j++)
          acc[i][j] = __builtin_amdgcn_mfma_f32_16x16x32_bf16(af[i], bf[j], acc[i][j], 0, 0, 0);
    }
  }
  // epilogue: LDS transpose, 32-n groups, coalesced float4 stores along l(=m)
  float* T = (float*)smem;               // [32][132] fp32
  int b = m0 >> 12, l0 = m0 & 4095;
  for(int g=0; g<4; ++g){
    __syncthreads();
    if((g >> 1) == (wave & 1)){
      int jg = g & 1;
      #pragma unroll
      for(int j2=0;j2<2;j2++){
        int j = jg*2 + j2;
        #pragma unroll
        for(int i=0;i<4;i++)
          #pragma unroll
          for(int r=0;r<4;r++){
            int ml = wm + i*16 + lk*4 + r;
            int nl = wn + j*16 + lm - g*32;
            T[nl*132 + ml] = acc[i][j][r];
          }
      }
    }
    __syncthreads();
    int nl = tid >> 3, seg = tid & 7;
    float* dst = &out[((size_t)b*DIM + n0 + g*32 + nl)*LEN + l0 + seg*16];
    #pragma unroll
    for(int k=0;k<4;k++){
      float4 v = *(const float4*)&T[nl*132 + seg*16 + k*4];
      *(float4*)&dst[k*4] = v;
    }
  }
}

extern "C" void kernel_launch(void* const* d_in, const int* in_sizes, int n_in,
                              void* d_out, int out_size, void* d_ws, size_t ws_size,
                              hipStream_t stream) {
  const float* x    = (const float*)d_in[0];
  const float* lnw  = (const float*)d_in[1];
  const float* lnb  = (const float*)d_in[2];
  const float* Win  = (const float*)d_in[3];
  const float* cw   = (const float*)d_in[4];
  const float* cb   = (const float*)d_in[5];
  const float* Wxp  = (const float*)d_in[6];
  const float* Wdt  = (const float*)d_in[7];
  const float* bdt  = (const float*)d_in[8];
  const float* Alog = (const float*)d_in[9];
  const float* Dp   = (const float*)d_in[10];
  const float* Wout = (const float*)d_in[11];
  float* out = (float*)d_out;
  float* ws  = (float*)d_ws;

  // workspace layout (float-slot offsets), total 147.3 MiB
  float*    mu   = ws;                         // 16384
  float*    rs   = ws + 16384;                 // 16384
  float*    xin  = ws + 32768;                 // 16,777,216 fp32 (dead after conv)
  float*    P    = xin;                        // alias: 2,097,152
  float*    E    = xin + 2097152;              // alias: 2,097,152 (Hs in-place)
  ushort_t* dhi  = (ushort_t*)(xin + 4194304); // alias: bf16 8,388,608 (4,194,304 slots)
  ushort_t* dlo  = (ushort_t*)(xin + 8388608); // alias: bf16 8,388,608
  ushort_t* sz   = (ushort_t*)(ws + 32768 + 16777216);            // bf16 16,777,216
  ushort_t* u    = (ushort_t*)(ws + 32768 + 16777216 + 8388608);  // bf16 16,777,216 (y overwrites)
  ushort_t* xnT  = (ushort_t*)(ws + 32768 + 16777216 + 16777216); // bf16 8,388,608
  float*    dbl  = (float*)xnT;                // alias after gemm1: 1,048,576 fp32
  ushort_t* Winb = (ushort_t*)(ws + 32768 + 16777216 + 16777216 + 4194304);
  ushort_t* Woutb= Winb + 1048576;
  ushort_t* Wxpb = Woutb + 524288;

  hipLaunchKernelGGL(ln_stats_k, dim3(256),     dim3(256), 0, stream, x, mu, rs);
  hipLaunchKernelGGL(wcvt_k,     dim3(6400),    dim3(256), 0, stream, Win, Wout, Wxp, Winb, Woutb, Wxpb);
  hipLaunchKernelGGL(xnt_k,      dim3(2048),    dim3(256), 0, stream, x, mu, rs, lnw, lnb, xnT);
  hipLaunchKernelGGL(gemm1_mfma, dim3(16,128),  dim3(256), 0, stream, xnT, Winb, xin, sz);
  hipLaunchKernelGGL(conv_silu_k,dim3(65536),   dim3(256), 0, stream, xin, cw, cb, u);
  hipLaunchKernelGGL(gemm2_mfma, dim3(128),     dim3(256), 0, stream, u, Wxpb, dbl);
  hipLaunchKernelGGL(scanA_k,    dim3(512),     dim3(256), 0, stream, u, dbl, Wdt, bdt, Alog, P, E, dhi, dlo);
  hipLaunchKernelGGL(scanB_k,    dim3(256),     dim3(256), 0, stream, P, E);
  hipLaunchKernelGGL(scanC_k,    dim3(512),     dim3(256), 0, stream, u, dbl, Alog, E, Dp, sz, dhi, dlo);
  hipLaunchKernelGGL(gemm4_mfma, dim3(4,128),   dim3(256), 0, stream, u, Woutb, out);
}

// Round 6
// 440.817 us; speedup vs baseline: 2.5326x; 1.1985x over previous
//
#include <hip/hip_runtime.h>
#include <math.h>

#define Bsz 4
#define DIM 512
#define LEN 4096
#define DST 16
#define DIN 1024
#define NCH 64    // chunks over L
#define CHL 64    // chunk length

typedef unsigned short ushort_t;
typedef unsigned int uint_t;
typedef __attribute__((ext_vector_type(8))) short short8;   // 8 bf16 (4 VGPRs)
typedef __attribute__((ext_vector_type(4))) float f32x4;

__device__ __forceinline__ float sigmoidf_(float x){ return 1.0f/(1.0f+__expf(-x)); }
__device__ __forceinline__ float bf2f(ushort_t u){ return __uint_as_float(((uint_t)u) << 16); }
__device__ __forceinline__ ushort_t f2bf(float f){
  uint_t x = __float_as_uint(f);
  uint_t r = (x + 0x7FFFu + ((x >> 16) & 1u)) >> 16;
  return (ushort_t)r;
}
__device__ __forceinline__ void gl2lds16(const void* g, void* l){
  __builtin_amdgcn_global_load_lds((const __attribute__((address_space(1))) void*)g,
                                   (__attribute__((address_space(3))) void*)l, 16, 0, 0);
}
// a^1..a^16 from a1=exp(-dv), log-depth
#define POW_CHAIN(av, a1) \
  { float a2=a1*a1, a4=a2*a2, a8=a4*a4; \
    av[0]=a1; av[1]=a2; av[2]=a2*a1; av[3]=a4; \
    av[4]=a4*a1; av[5]=a4*a2; av[6]=a4*av[2]; av[7]=a8; \
    av[8]=a8*a1; av[9]=a8*a2; av[10]=a8*av[2]; av[11]=a8*a4; \
    av[12]=a8*av[4]; av[13]=a8*av[5]; av[14]=a8*av[6]; av[15]=a8*a8; }

// load nA with snapping: if nA[s] ~= -(s+1) for all s, snap exactly and report fast=true
__device__ __forceinline__ bool load_nA(const float* Alog, int d, float* nA){
  bool fast = true;
  #pragma unroll
  for(int s=0;s<DST;s++){
    float v = -__expf(Alog[d*DST+s]);
    float tgt = -(float)(s+1);
    if(fabsf(v - tgt) < 1e-4f*(float)(s+1)) v = tgt;
    else fast = false;
    nA[s] = v;
  }
  return fast;
}

// ---------------- LayerNorm stats ----------------
__global__ __launch_bounds__(256) void ln_stats_k(const float* __restrict__ x,
                                                  float* __restrict__ mu, float* __restrict__ rs){
  int bid = blockIdx.x;
  int b = bid >> 6;
  int lg = bid & 63;
  int lane = threadIdx.x & 63;
  int g = threadIdx.x >> 6;
  int l = lg*64 + lane;
  const float* xb = x + (size_t)b*DIM*LEN + l;
  float s = 0.f, sq = 0.f;
  for(int d = g*128; d < g*128 + 128; ++d){
    float v = xb[(size_t)d*LEN];
    s += v; sq += v*v;
  }
  __shared__ float rsum[4][64], rsq[4][64];
  rsum[g][lane] = s; rsq[g][lane] = sq;
  __syncthreads();
  if(threadIdx.x < 64){
    float ts = 0.f, tq = 0.f;
    for(int gg=0; gg<4; ++gg){ ts += rsum[gg][lane]; tq += rsq[gg][lane]; }
    float m = ts * (1.0f/DIM);
    float var = tq * (1.0f/DIM) - m*m;
    mu[b*LEN + l] = m;
    rs[b*LEN + l] = rsqrtf(var + 1e-5f);
  }
}

// ---------------- weights -> bf16 ----------------
__global__ __launch_bounds__(256) void wcvt_k(const float* __restrict__ Win,
    const float* __restrict__ Wout, const float* __restrict__ Wxp,
    ushort_t* __restrict__ Winb, ushort_t* __restrict__ Woutb, ushort_t* __restrict__ Wxpb){
  int i = blockIdx.x*256 + threadIdx.x;   // 1,638,400 total
  if(i < 1048576) Winb[i] = f2bf(Win[i]);
  else if(i < 1572864) Woutb[i-1048576] = f2bf(Wout[i-1048576]);
  else if(i < 1638400) Wxpb[i-1572864] = f2bf(Wxp[i-1572864]);
}

// ---------------- LN apply + transpose -> xnT bf16 [B*L][512] ----------------
__global__ __launch_bounds__(256) void xnt_k(const float* __restrict__ x,
    const float* __restrict__ mu, const float* __restrict__ rs,
    const float* __restrict__ lnw, const float* __restrict__ lnb, ushort_t* __restrict__ xnT){
  __shared__ ushort_t t[64][72];
  int bid = blockIdx.x;              // 4 * 8 * 64 = 2048
  int lt = bid & 63;
  int dt_ = (bid >> 6) & 7;
  int b = bid >> 9;
  int l0 = lt*64, d0 = dt_*64;
  int ll = threadIdx.x & 63;
  int dq = threadIdx.x >> 6;
  float mul_ = mu[b*LEN + l0 + ll], rsl = rs[b*LEN + l0 + ll];
  const float* xb = x + (size_t)b*DIM*LEN;
  #pragma unroll
  for(int i=0;i<16;i++){
    int d = d0 + dq*16 + i;
    float v = xb[(size_t)d*LEN + l0 + ll];
    t[ll][dq*16 + i] = f2bf((v - mul_)*rsl*lnw[d] + lnb[d]);
  }
  __syncthreads();
  int lr = threadIdx.x >> 2, seg = threadIdx.x & 3;
  ushort_t* dst = &xnT[(size_t)(b*LEN + l0 + lr)*DIM + d0 + seg*16];
  #pragma unroll
  for(int k=0;k<4;k++){
    ushort4 v = *(const ushort4*)&t[lr][seg*16 + k*4];
    *(ushort4*)&dst[k*4] = v;
  }
}

// ---------------- GEMM1 MFMA: xnT[16384][512] x Winb[2048][512] -> xin fp32 / sz bf16 ----------------
__global__ __launch_bounds__(256) void gemm1_mfma(const ushort_t* __restrict__ A,
    const ushort_t* __restrict__ Bw, float* __restrict__ xin, ushort_t* __restrict__ sz){
  __shared__ __align__(16) ushort_t As[128*64];
  __shared__ __align__(16) ushort_t Bs[128*64];
  int tid = threadIdx.x;
  int wave = tid >> 6, lane = tid & 63;
  int n0 = blockIdx.x * 128;
  int m0 = blockIdx.y * 128;
  int wm = (wave >> 1) * 64, wn = (wave & 1) * 64;
  int lm = lane & 15;
  int lk = lane >> 4;
  f32x4 zero4 = {0.f,0.f,0.f,0.f};
  f32x4 acc[4][4];
  #pragma unroll
  for(int i=0;i<4;i++)
    #pragma unroll
    for(int j=0;j<4;j++) acc[i][j] = zero4;
  for(int k0=0; k0<512; k0+=64){
    __syncthreads();
    #pragma unroll
    for(int i=0;i<4;i++){
      int c = i*256 + tid;
      int r = c >> 3, kc = c & 7;
      gl2lds16(&A [(size_t)(m0 + r)*512 + k0 + kc*8], &As[c*8]);
      gl2lds16(&Bw[(size_t)(n0 + r)*512 + k0 + kc*8], &Bs[c*8]);
    }
    __syncthreads();
    #pragma unroll
    for(int kk=0; kk<64; kk+=32){
      short8 af[4], bf[4];
      #pragma unroll
      for(int i=0;i<4;i++){
        af[i] = *(const short8*)&As[(wm + i*16 + lm)*64 + kk + lk*8];
        bf[i] = *(const short8*)&Bs[(wn + i*16 + lm)*64 + kk + lk*8];
      }
      #pragma unroll
      for(int i=0;i<4;i++)
        #pragma unroll
        for(int j=0;j<4;j++)
          acc[i][j] = __builtin_amdgcn_mfma_f32_16x16x32_bf16(af[i], bf[j], acc[i][j], 0, 0, 0);
    }
  }
  bool is_z = (n0 >= 1024);
  #pragma unroll
  for(int i=0;i<4;i++)
    #pragma unroll
    for(int j=0;j<4;j++)
      #pragma unroll
      for(int r=0;r<4;r++){
        int m = m0 + wm + i*16 + lk*4 + r;
        int n = n0 + wn + j*16 + lm;
        float v = acc[i][j][r];
        if(!is_z) xin[(size_t)m*DIN + n] = v;
        else      sz[(size_t)m*DIN + (n-1024)] = f2bf(v * sigmoidf_(v));
      }
}

// ---------------- conv1d + SiLU -> u bf16 ----------------
__global__ __launch_bounds__(256) void conv_silu_k(const float* __restrict__ xin,
    const float* __restrict__ cw, const float* __restrict__ cb, ushort_t* __restrict__ u){
  int idx = blockIdx.x*256 + threadIdx.x;
  int d = idx & 1023;
  int r = idx >> 10;
  int l = r & 4095;
  int b = r >> 12;
  float acc = cb[d];
  const float* base = xin + (size_t)b*LEN*DIN + d;
  #pragma unroll
  for(int j=0;j<4;j++){
    int ls = l - 3 + j;
    if(ls >= 0) acc += base[(size_t)ls*DIN] * cw[d*4+j];
  }
  u[idx] = f2bf(acc * sigmoidf_(acc));
}

// ---------------- GEMM2 MFMA: u[16384][1024] x Wxpb[64][1024] -> dbl fp32 [16384][64] ----------------
__global__ __launch_bounds__(256) void gemm2_mfma(const ushort_t* __restrict__ A,
    const ushort_t* __restrict__ Bw, float* __restrict__ dbl){
  __shared__ __align__(16) ushort_t As[128*64];
  __shared__ __align__(16) ushort_t Bs[64*64];
  int tid = threadIdx.x;
  int wave = tid >> 6, lane = tid & 63;
  int m0 = blockIdx.x * 128;
  int wm = (wave >> 1) * 64, wn = (wave & 1) * 32;
  int lm = lane & 15;
  int lk = lane >> 4;
  f32x4 zero4 = {0.f,0.f,0.f,0.f};
  f32x4 acc[4][2];
  #pragma unroll
  for(int i=0;i<4;i++){ acc[i][0] = zero4; acc[i][1] = zero4; }
  for(int k0=0; k0<1024; k0+=64){
    __syncthreads();
    #pragma unroll
    for(int i=0;i<4;i++){
      int c = i*256 + tid;
      int r = c >> 3, kc = c & 7;
      gl2lds16(&A[(size_t)(m0 + r)*1024 + k0 + kc*8], &As[c*8]);
    }
    #pragma unroll
    for(int i=0;i<2;i++){
      int c = i*256 + tid;
      int r = c >> 3, kc = c & 7;
      gl2lds16(&Bw[(size_t)r*1024 + k0 + kc*8], &Bs[c*8]);
    }
    __syncthreads();
    #pragma unroll
    for(int kk=0; kk<64; kk+=32){
      short8 af[4], bf[2];
      #pragma unroll
      for(int i=0;i<4;i++) af[i] = *(const short8*)&As[(wm + i*16 + lm)*64 + kk + lk*8];
      #pragma unroll
      for(int j=0;j<2;j++) bf[j] = *(const short8*)&Bs[(wn + j*16 + lm)*64 + kk + lk*8];
      #pragma unroll
      for(int i=0;i<4;i++)
        #pragma unroll
        for(int j=0;j<2;j++)
          acc[i][j] = __builtin_amdgcn_mfma_f32_16x16x32_bf16(af[i], bf[j], acc[i][j], 0, 0, 0);
    }
  }
  #pragma unroll
  for(int i=0;i<4;i++)
    #pragma unroll
    for(int j=0;j<2;j++)
      #pragma unroll
      for(int r=0;r<4;r++){
        int m = m0 + wm + i*16 + lk*4 + r;
        int n = wn + j*16 + lm;
        dbl[(size_t)m*64 + n] = acc[i][j][r];
      }
}

// ---------------- deltag: dv[m,d] = softplus(dbl[m,0:32]·Wdt[d,:]+bdt[d]) -> fp16 ----------------
__global__ __launch_bounds__(256,4) void deltag_k(const float* __restrict__ dbl,
    const float* __restrict__ Wdt, const float* __restrict__ bdt,
    _Float16* __restrict__ dF){
  __shared__ __align__(16) float dts[64*32];
  int bid = blockIdx.x;              // 256 m-tiles x 4 d-tiles = 1024
  int d0 = (bid & 3) * 256;
  int m0 = (bid >> 2) * 64;
  int tid = threadIdx.x;
  const f32x4* src4 = (const f32x4*)(dbl + (size_t)m0*64);
  f32x4* dst4 = (f32x4*)dts;
  for(int i=tid; i<64*8; i+=256){
    int row = i >> 3, q = i & 7;
    dst4[i] = src4[row*16 + q];
  }
  int d = d0 + tid;
  float w[32];
  #pragma unroll
  for(int k=0;k<32;k+=4){
    float4 t4 = *(const float4*)&Wdt[d*32+k];
    w[k]=t4.x; w[k+1]=t4.y; w[k+2]=t4.z; w[k+3]=t4.w;
  }
  float bd = bdt[d];
  __syncthreads();
  for(int m=0;m<64;m++){
    const float* row = dts + m*32;
    float dtv = bd;
    #pragma unroll
    for(int k=0;k<32;k+=4){
      f32x4 q = *(const f32x4*)&row[k];
      dtv += q.x*w[k] + q.y*w[k+1] + q.z*w[k+2] + q.w*w[k+3];
    }
    float dv = dtv > 15.f ? dtv : __logf(1.f + __expf(dtv));
    dF[(size_t)(m0+m)*DIN + d] = (_Float16)dv;
  }
}

// ---------------- scan phase A: per-chunk local end state + cumD ----------------
__global__ __launch_bounds__(256,4) void scanA_k(const ushort_t* __restrict__ u,
    const float* __restrict__ dbl, const float* __restrict__ Alog,
    const _Float16* __restrict__ dF,
    float* __restrict__ E, float* __restrict__ cum){
  __shared__ __align__(16) float dch[CHL*16];   // B cols
  int bid = blockIdx.x;            // NCH*4*Bsz = 1024
  int c = bid & (NCH-1);
  int dblk = (bid >> 6) & 3;
  int b = bid >> 8;
  int d = dblk*256 + threadIdx.x;
  const f32x4* src = (const f32x4*)(dbl + ((size_t)b*LEN + c*CHL)*64);
  f32x4* dst4 = (f32x4*)dch;
  for(int i=threadIdx.x; i<CHL*4; i+=256){
    int t = i >> 2, q = i & 3;
    dst4[i] = src[t*16 + 8 + q];
  }
  float nA[DST];
  bool fast = load_nA(Alog, d, nA);
  float Es[DST];
  #pragma unroll
  for(int s=0;s<DST;s++) Es[s] = 0.f;
  float cumD = 0.f;
  __syncthreads();
  const ushort_t*  uu = u  + ((size_t)b*LEN + c*CHL)*DIN + d;
  const _Float16*  pd = dF + ((size_t)b*LEN + c*CHL)*DIN + d;
  if(fast){
    for(int t=0;t<CHL;++t){
      float dv = (float)pd[(size_t)t*DIN];
      float uv = bf2f(uu[(size_t)t*DIN]);
      float du = dv*uv;
      cumD += dv;
      float a1 = __expf(-dv);
      float av[DST];
      POW_CHAIN(av, a1);
      const f32x4* r4 = (const f32x4*)(dch + t*16);
      f32x4 B0=r4[0], B1=r4[1], B2=r4[2], B3=r4[3];
      Es[0]=av[0]*Es[0]+du*B0.x;  Es[1]=av[1]*Es[1]+du*B0.y;
      Es[2]=av[2]*Es[2]+du*B0.z;  Es[3]=av[3]*Es[3]+du*B0.w;
      Es[4]=av[4]*Es[4]+du*B1.x;  Es[5]=av[5]*Es[5]+du*B1.y;
      Es[6]=av[6]*Es[6]+du*B1.z;  Es[7]=av[7]*Es[7]+du*B1.w;
      Es[8]=av[8]*Es[8]+du*B2.x;  Es[9]=av[9]*Es[9]+du*B2.y;
      Es[10]=av[10]*Es[10]+du*B2.z; Es[11]=av[11]*Es[11]+du*B2.w;
      Es[12]=av[12]*Es[12]+du*B3.x; Es[13]=av[13]*Es[13]+du*B3.y;
      Es[14]=av[14]*Es[14]+du*B3.z; Es[15]=av[15]*Es[15]+du*B3.w;
    }
  } else {
    for(int t=0;t<CHL;++t){
      float dv = (float)pd[(size_t)t*DIN];
      float uv = bf2f(uu[(size_t)t*DIN]);
      float du = dv*uv;
      cumD += dv;
      const float* row = dch + t*16;
      #pragma unroll
      for(int s=0;s<DST;s++){
        float a = __expf(dv*nA[s]);
        Es[s] = a*Es[s] + du*row[s];
      }
    }
  }
  size_t o = (size_t)(b*NCH + c)*DST*DIN + d;
  #pragma unroll
  for(int s=0;s<DST;s++) E[o + (size_t)s*DIN] = Es[s];
  cum[(size_t)(b*NCH + c)*DIN + d] = cumD;
}

// ---------------- scan phase B: combine chunk boundaries; Hs in-place over E ----------------
__global__ __launch_bounds__(256) void scanB_k(const float* __restrict__ cum,
    const float* __restrict__ Alog, float* __restrict__ E){
  int g = blockIdx.x*256 + threadIdx.x;   // 65536 = Bsz*DST*DIN
  int d = g & 1023;
  int s = (g >> 10) & 15;
  int b = g >> 14;
  float v = -__expf(Alog[d*DST + s]);
  float tgt = -(float)(s+1);
  float nA = (fabsf(v - tgt) < 1e-4f*(float)(s+1)) ? tgt : v;
  float h = 0.f;
  for(int c=0;c<NCH;c++){
    float p = __expf(cum[(size_t)(b*NCH + c)*DIN + d] * nA);
    size_t o = (size_t)((b*NCH + c)*DST + s)*DIN + d;
    float e = E[o];
    E[o] = h;
    h = p*h + e;
  }
}

// ---------------- scan phase C: replay, y=(scan+u*D)*sz, y bf16 over u ----------------
__global__ __launch_bounds__(256,4) void scanC_k(ushort_t* __restrict__ u,
    const float* __restrict__ dbl, const float* __restrict__ Alog,
    const float* __restrict__ Hs, const float* __restrict__ Dp, const ushort_t* __restrict__ sz,
    const _Float16* __restrict__ dF){
  __shared__ __align__(16) float dch[CHL*32];   // B,C cols
  int bid = blockIdx.x;
  int c = bid & (NCH-1);
  int dblk = (bid >> 6) & 3;
  int b = bid >> 8;
  int d = dblk*256 + threadIdx.x;
  const f32x4* src = (const f32x4*)(dbl + ((size_t)b*LEN + c*CHL)*64);
  f32x4* dst4 = (f32x4*)dch;
  for(int i=threadIdx.x; i<CHL*8; i+=256){
    int t = i >> 3, q = i & 7;
    dst4[i] = src[t*16 + 8 + q];
  }
  float nA[DST];
  bool fast = load_nA(Alog, d, nA);
  float h[DST];
  size_t ho = (size_t)(b*NCH + c)*DST*DIN + d;
  #pragma unroll
  for(int s=0;s<DST;s++) h[s] = Hs[ho + (size_t)s*DIN];
  float Dv = Dp[d];
  __syncthreads();
  ushort_t* uu = u + ((size_t)b*LEN + c*CHL)*DIN + d;
  const ushort_t* zz = sz + ((size_t)b*LEN + c*CHL)*DIN + d;
  const _Float16* pd = dF + ((size_t)b*LEN + c*CHL)*DIN + d;
  if(fast){
    for(int t=0;t<CHL;++t){
      float dv = (float)pd[(size_t)t*DIN];
      float uv = bf2f(uu[(size_t)t*DIN]);
      float du = dv*uv;
      float a1 = __expf(-dv);
      float av[DST];
      POW_CHAIN(av, a1);
      const f32x4* r4 = (const f32x4*)(dch + t*32);
      f32x4 B0=r4[0], B1=r4[1], B2=r4[2], B3=r4[3];
      f32x4 C0=r4[4], C1=r4[5], C2=r4[6], C3=r4[7];
      float y0, y1, y2, y3;
      h[0]=av[0]*h[0]+du*B0.x;  h[1]=av[1]*h[1]+du*B0.y;
      h[2]=av[2]*h[2]+du*B0.z;  h[3]=av[3]*h[3]+du*B0.w;
      y0 = h[0]*C0.x + h[1]*C0.y; y1 = h[2]*C0.z + h[3]*C0.w;
      h[4]=av[4]*h[4]+du*B1.x;  h[5]=av[5]*h[5]+du*B1.y;
      h[6]=av[6]*h[6]+du*B1.z;  h[7]=av[7]*h[7]+du*B1.w;
      y2 = h[4]*C1.x + h[5]*C1.y; y3 = h[6]*C1.z + h[7]*C1.w;
      h[8]=av[8]*h[8]+du*B2.x;  h[9]=av[9]*h[9]+du*B2.y;
      h[10]=av[10]*h[10]+du*B2.z; h[11]=av[11]*h[11]+du*B2.w;
      y0 += h[8]*C2.x + h[9]*C2.y; y1 += h[10]*C2.z + h[11]*C2.w;
      h[12]=av[12]*h[12]+du*B3.x; h[13]=av[13]*h[13]+du*B3.y;
      h[14]=av[14]*h[14]+du*B3.z; h[15]=av[15]*h[15]+du*B3.w;
      y2 += h[12]*C3.x + h[13]*C3.y; y3 += h[14]*C3.z + h[15]*C3.w;
      float y = (y0+y1) + (y2+y3) + uv*Dv;
      y *= bf2f(zz[(size_t)t*DIN]);
      uu[(size_t)t*DIN] = f2bf(y);
    }
  } else {
    for(int t=0;t<CHL;++t){
      float dv = (float)pd[(size_t)t*DIN];
      float uv = bf2f(uu[(size_t)t*DIN]);
      float du = dv*uv;
      const float* row = dch + t*32;
      float y = 0.f;
      #pragma unroll
      for(int s=0;s<DST;s++){
        float a = __expf(dv*nA[s]);
        h[s] = a*h[s] + du*row[s];
        y += h[s]*row[16+s];
      }
      y += uv*Dv;
      y *= bf2f(zz[(size_t)t*DIN]);
      uu[(size_t)t*DIN] = f2bf(y);
    }
  }
}

// ---------------- GEMM4 MFMA: y[16384][1024] x Woutb[512][1024] -> out[b][n][l] ----------------
__global__ __launch_bounds__(256) void gemm4_mfma(const ushort_t* __restrict__ A,
    const ushort_t* __restrict__ Bw, float* __restrict__ out){
  __shared__ __align__(16) ushort_t smem[2*128*64];   // As | Bs ; epilogue reuses as float
  ushort_t* As = smem;
  ushort_t* Bs = smem + 128*64;
  int tid = threadIdx.x;
  int wave = tid >> 6, lane = tid & 63;
  int n0 = blockIdx.x * 128;       // N=512 -> 4
  int m0 = blockIdx.y * 128;
  int wm = (wave >> 1) * 64, wn = (wave & 1) * 64;
  int lm = lane & 15;
  int lk = lane >> 4;
  f32x4 zero4 = {0.f,0.f,0.f,0.f};
  f32x4 acc[4][4];
  #pragma unroll
  for(int i=0;i<4;i++)
    #pragma unroll
    for(int j=0;j<4;j++) acc[i][j] = zero4;
  for(int k0=0; k0<1024; k0+=64){
    __syncthreads();
    #pragma unroll
    for(int i=0;i<4;i++){
      int c = i*256 + tid;
      int r = c >> 3, kc = c & 7;
      gl2lds16(&A [(size_t)(m0 + r)*1024 + k0 + kc*8], &As[c*8]);
      gl2lds16(&Bw[(size_t)(n0 + r)*1024 + k0 + kc*8], &Bs[c*8]);
    }
    __syncthreads();
    #pragma unroll
    for(int kk=0; kk<64; kk+=32){
      short8 af[4], bf[4];
      #pragma unroll
      for(int i=0;i<4;i++){
        af[i] = *(const short8*)&As[(wm + i*16 + lm)*64 + kk + lk*8];
        bf[i] = *(const short8*)&Bs[(wn + i*16 + lm)*64 + kk + lk*8];
      }
      #pragma unroll
      for(int i=0;i<4;i++)
        #pragma unroll
        for(int j=0;j<4;j++)
          acc[i][j] = __builtin_amdgcn_mfma_f32_16x16x32_bf16(af[i], bf[j], acc[i][j], 0, 0, 0);
    }
  }
  // epilogue: LDS transpose, 32-n groups, coalesced float4 stores along l(=m)
  float* T = (float*)smem;               // [32][132] fp32
  int b = m0 >> 12, l0 = m0 & 4095;
  for(int g=0; g<4; ++g){
    __syncthreads();
    if((g >> 1) == (wave & 1)){
      int jg = g & 1;
      #pragma unroll
      for(int j2=0;j2<2;j2++){
        int j = jg*2 + j2;
        #pragma unroll
        for(int i=0;i<4;i++)
          #pragma unroll
          for(int r=0;r<4;r++){
            int ml = wm + i*16 + lk*4 + r;
            int nl = wn + j*16 + lm - g*32;
            T[nl*132 + ml] = acc[i][j][r];
          }
      }
    }
    __syncthreads();
    int nl = tid >> 3, seg = tid & 7;
    float* dst = &out[((size_t)b*DIM + n0 + g*32 + nl)*LEN + l0 + seg*16];
    #pragma unroll
    for(int k=0;k<4;k++){
      float4 v = *(const float4*)&T[nl*132 + seg*16 + k*4];
      *(float4*)&dst[k*4] = v;
    }
  }
}

extern "C" void kernel_launch(void* const* d_in, const int* in_sizes, int n_in,
                              void* d_out, int out_size, void* d_ws, size_t ws_size,
                              hipStream_t stream) {
  const float* x    = (const float*)d_in[0];
  const float* lnw  = (const float*)d_in[1];
  const float* lnb  = (const float*)d_in[2];
  const float* Win  = (const float*)d_in[3];
  const float* cw   = (const float*)d_in[4];
  const float* cb   = (const float*)d_in[5];
  const float* Wxp  = (const float*)d_in[6];
  const float* Wdt  = (const float*)d_in[7];
  const float* bdt  = (const float*)d_in[8];
  const float* Alog = (const float*)d_in[9];
  const float* Dp   = (const float*)d_in[10];
  const float* Wout = (const float*)d_in[11];
  float* out = (float*)d_out;
  float* ws  = (float*)d_ws;

  // workspace layout (float-slot offsets), total 147.25 MiB — NO overlapping live ranges:
  //   region1 [32768, 32768+16777216): xin fp32 (live ln..conv), then:
  //     dF fp16 [  +0, +8388608)   16,777,216 halves
  //     E  fp32 [+8388608, +12582912)
  //     cum     [+12582912, +12845056)
  float*    mu   = ws;                          // 16384
  float*    rs   = ws + 16384;                  // 16384
  float*    xin  = ws + 32768;                  // 16,777,216 fp32
  _Float16* dF   = (_Float16*)xin;              // 8,388,608 fl slots
  float*    E    = xin + 8388608;               // 4,194,304 fl (Hs in-place)
  float*    cum  = xin + 12582912;              // 262,144 fl
  ushort_t* sz   = (ushort_t*)(ws + 32768 + 16777216);            // bf16 16,777,216
  ushort_t* u    = (ushort_t*)(ws + 32768 + 16777216 + 8388608);  // bf16 16,777,216 (y overwrites)
  ushort_t* xnT  = (ushort_t*)(ws + 32768 + 16777216 + 16777216); // bf16 8,388,608
  float*    dbl  = (float*)xnT;                 // alias after gemm1: 1,048,576 fp32
  ushort_t* Winb = (ushort_t*)(ws + 32768 + 16777216 + 16777216 + 4194304);
  ushort_t* Woutb= Winb + 1048576;
  ushort_t* Wxpb = Woutb + 524288;

  hipLaunchKernelGGL(ln_stats_k, dim3(256),     dim3(256), 0, stream, x, mu, rs);
  hipLaunchKernelGGL(wcvt_k,     dim3(6400),    dim3(256), 0, stream, Win, Wout, Wxp, Winb, Woutb, Wxpb);
  hipLaunchKernelGGL(xnt_k,      dim3(2048),    dim3(256), 0, stream, x, mu, rs, lnw, lnb, xnT);
  hipLaunchKernelGGL(gemm1_mfma, dim3(16,128),  dim3(256), 0, stream, xnT, Winb, xin, sz);
  hipLaunchKernelGGL(conv_silu_k,dim3(65536),   dim3(256), 0, stream, xin, cw, cb, u);
  hipLaunchKernelGGL(gemm2_mfma, dim3(128),     dim3(256), 0, stream, u, Wxpb, dbl);
  hipLaunchKernelGGL(deltag_k,   dim3(1024),    dim3(256), 0, stream, dbl, Wdt, bdt, dF);
  hipLaunchKernelGGL(scanA_k,    dim3(1024),    dim3(256), 0, stream, u, dbl, Alog, dF, E, cum);
  hipLaunchKernelGGL(scanB_k,    dim3(256),     dim3(256), 0, stream, cum, Alog, E);
  hipLaunchKernelGGL(scanC_k,    dim3(1024),    dim3(256), 0, stream, u, dbl, Alog, E, Dp, sz, dF);
  hipLaunchKernelGGL(gemm4_mfma, dim3(4,128),   dim3(256), 0, stream, u, Woutb, out);
}

// Round 7
// 427.244 us; speedup vs baseline: 2.6130x; 1.0318x over previous
//
#include <hip/hip_runtime.h>
#include <math.h>

#define Bsz 4
#define DIM 512
#define LEN 4096
#define DST 16
#define DIN 1024
#define NCH 64    // chunks over L
#define CHL 64    // chunk length

typedef unsigned short ushort_t;
typedef unsigned int uint_t;
typedef __attribute__((ext_vector_type(8))) short short8;     // 8 bf16 (4 VGPRs)
typedef __attribute__((ext_vector_type(8))) _Float16 half8;   // 8 fp16
typedef __attribute__((ext_vector_type(4))) float f32x4;

__device__ __forceinline__ float sigmoidf_(float x){ return 1.0f/(1.0f+__expf(-x)); }
__device__ __forceinline__ float bf2f(ushort_t u){ return __uint_as_float(((uint_t)u) << 16); }
__device__ __forceinline__ ushort_t f2bf(float f){
  uint_t x = __float_as_uint(f);
  uint_t r = (x + 0x7FFFu + ((x >> 16) & 1u)) >> 16;
  return (ushort_t)r;
}
__device__ __forceinline__ void gl2lds16(const void* g, void* l){
  __builtin_amdgcn_global_load_lds((const __attribute__((address_space(1))) void*)g,
                                   (__attribute__((address_space(3))) void*)l, 16, 0, 0);
}
// a^1..a^16 from a1=exp(-dv), log-depth
#define POW_CHAIN(av, a1) \
  { float a2=a1*a1, a4=a2*a2, a8=a4*a4; \
    av[0]=a1; av[1]=a2; av[2]=a2*a1; av[3]=a4; \
    av[4]=a4*a1; av[5]=a4*a2; av[6]=a4*av[2]; av[7]=a8; \
    av[8]=a8*a1; av[9]=a8*a2; av[10]=a8*av[2]; av[11]=a8*a4; \
    av[12]=a8*av[4]; av[13]=a8*av[5]; av[14]=a8*av[6]; av[15]=a8*a8; }

// load nA with snapping: if nA[s] ~= -(s+1) for all s, snap exactly and report fast=true
__device__ __forceinline__ bool load_nA(const float* Alog, int d, float* nA){
  bool fast = true;
  #pragma unroll
  for(int s=0;s<DST;s++){
    float v = -__expf(Alog[d*DST+s]);
    float tgt = -(float)(s+1);
    if(fabsf(v - tgt) < 1e-4f*(float)(s+1)) v = tgt;
    else fast = false;
    nA[s] = v;
  }
  return fast;
}

// ---------------- LayerNorm stats ----------------
__global__ __launch_bounds__(256) void ln_stats_k(const float* __restrict__ x,
                                                  float* __restrict__ mu, float* __restrict__ rs){
  int bid = blockIdx.x;
  int b = bid >> 6;
  int lg = bid & 63;
  int lane = threadIdx.x & 63;
  int g = threadIdx.x >> 6;
  int l = lg*64 + lane;
  const float* xb = x + (size_t)b*DIM*LEN + l;
  float s = 0.f, sq = 0.f;
  for(int d = g*128; d < g*128 + 128; ++d){
    float v = xb[(size_t)d*LEN];
    s += v; sq += v*v;
  }
  __shared__ float rsum[4][64], rsq[4][64];
  rsum[g][lane] = s; rsq[g][lane] = sq;
  __syncthreads();
  if(threadIdx.x < 64){
    float ts = 0.f, tq = 0.f;
    for(int gg=0; gg<4; ++gg){ ts += rsum[gg][lane]; tq += rsq[gg][lane]; }
    float m = ts * (1.0f/DIM);
    float var = tq * (1.0f/DIM) - m*m;
    mu[b*LEN + l] = m;
    rs[b*LEN + l] = rsqrtf(var + 1e-5f);
  }
}

// ---------------- weights -> bf16 ----------------
__global__ __launch_bounds__(256) void wcvt_k(const float* __restrict__ Win,
    const float* __restrict__ Wout, const float* __restrict__ Wxp,
    ushort_t* __restrict__ Winb, ushort_t* __restrict__ Woutb, ushort_t* __restrict__ Wxpb){
  int i = blockIdx.x*256 + threadIdx.x;   // 1,638,400 total
  if(i < 1048576) Winb[i] = f2bf(Win[i]);
  else if(i < 1572864) Woutb[i-1048576] = f2bf(Wout[i-1048576]);
  else if(i < 1638400) Wxpb[i-1572864] = f2bf(Wxp[i-1572864]);
}

// ---------------- LN apply + transpose -> xnT bf16 [B*L][512] ----------------
__global__ __launch_bounds__(256) void xnt_k(const float* __restrict__ x,
    const float* __restrict__ mu, const float* __restrict__ rs,
    const float* __restrict__ lnw, const float* __restrict__ lnb, ushort_t* __restrict__ xnT){
  __shared__ ushort_t t[64][72];
  int bid = blockIdx.x;              // 4 * 8 * 64 = 2048
  int lt = bid & 63;
  int dt_ = (bid >> 6) & 7;
  int b = bid >> 9;
  int l0 = lt*64, d0 = dt_*64;
  int ll = threadIdx.x & 63;
  int dq = threadIdx.x >> 6;
  float mul_ = mu[b*LEN + l0 + ll], rsl = rs[b*LEN + l0 + ll];
  const float* xb = x + (size_t)b*DIM*LEN;
  #pragma unroll
  for(int i=0;i<16;i++){
    int d = d0 + dq*16 + i;
    float v = xb[(size_t)d*LEN + l0 + ll];
    t[ll][dq*16 + i] = f2bf((v - mul_)*rsl*lnw[d] + lnb[d]);
  }
  __syncthreads();
  int lr = threadIdx.x >> 2, seg = threadIdx.x & 3;
  ushort_t* dst = &xnT[(size_t)(b*LEN + l0 + lr)*DIM + d0 + seg*16];
  #pragma unroll
  for(int k=0;k<4;k++){
    ushort4 v = *(const ushort4*)&t[lr][seg*16 + k*4];
    *(ushort4*)&dst[k*4] = v;
  }
}

// ---------------- GEMM1 MFMA: xnT[16384][512] x Winb[2048][512] -> xin fp16 / sz bf16 ----------------
__global__ __launch_bounds__(256) void gemm1_mfma(const ushort_t* __restrict__ A,
    const ushort_t* __restrict__ Bw, _Float16* __restrict__ xin, ushort_t* __restrict__ sz){
  __shared__ __align__(16) ushort_t As[128*64];
  __shared__ __align__(16) ushort_t Bs[128*64];
  int tid = threadIdx.x;
  int wave = tid >> 6, lane = tid & 63;
  int n0 = blockIdx.x * 128;
  int m0 = blockIdx.y * 128;
  int wm = (wave >> 1) * 64, wn = (wave & 1) * 64;
  int lm = lane & 15;
  int lk = lane >> 4;
  f32x4 zero4 = {0.f,0.f,0.f,0.f};
  f32x4 acc[4][4];
  #pragma unroll
  for(int i=0;i<4;i++)
    #pragma unroll
    for(int j=0;j<4;j++) acc[i][j] = zero4;
  for(int k0=0; k0<512; k0+=64){
    __syncthreads();
    #pragma unroll
    for(int i=0;i<4;i++){
      int c = i*256 + tid;
      int r = c >> 3, kc = c & 7;
      gl2lds16(&A [(size_t)(m0 + r)*512 + k0 + kc*8], &As[c*8]);
      gl2lds16(&Bw[(size_t)(n0 + r)*512 + k0 + kc*8], &Bs[c*8]);
    }
    __syncthreads();
    #pragma unroll
    for(int kk=0; kk<64; kk+=32){
      short8 af[4], bf[4];
      #pragma unroll
      for(int i=0;i<4;i++){
        af[i] = *(const short8*)&As[(wm + i*16 + lm)*64 + kk + lk*8];
        bf[i] = *(const short8*)&Bs[(wn + i*16 + lm)*64 + kk + lk*8];
      }
      #pragma unroll
      for(int i=0;i<4;i++)
        #pragma unroll
        for(int j=0;j<4;j++)
          acc[i][j] = __builtin_amdgcn_mfma_f32_16x16x32_bf16(af[i], bf[j], acc[i][j], 0, 0, 0);
    }
  }
  bool is_z = (n0 >= 1024);
  #pragma unroll
  for(int i=0;i<4;i++)
    #pragma unroll
    for(int j=0;j<4;j++)
      #pragma unroll
      for(int r=0;r<4;r++){
        int m = m0 + wm + i*16 + lk*4 + r;
        int n = n0 + wn + j*16 + lm;
        float v = acc[i][j][r];
        if(!is_z) xin[(size_t)m*DIN + n] = (_Float16)v;
        else      sz[(size_t)m*DIN + (n-1024)] = f2bf(v * sigmoidf_(v));
      }
}

// ---------------- conv1d + SiLU -> u bf16 (8 d per thread, vectorized) ----------------
__global__ __launch_bounds__(256) void conv_silu_k(const _Float16* __restrict__ xin,
    const float* __restrict__ cw, const float* __restrict__ cb, ushort_t* __restrict__ u){
  int idx = blockIdx.x*256 + threadIdx.x;   // 2,097,152 threads: (b,l,dgrp)
  int dg = idx & 127;
  int l  = (idx >> 7) & 4095;
  int b  = idx >> 19;
  int d0 = dg*8;
  float acc[8];
  #pragma unroll
  for(int k=0;k<8;k+=4){
    float4 c4 = *(const float4*)&cb[d0+k];
    acc[k]=c4.x; acc[k+1]=c4.y; acc[k+2]=c4.z; acc[k+3]=c4.w;
  }
  float w[8][4];
  #pragma unroll
  for(int k=0;k<8;k++){
    float4 c4 = *(const float4*)&cw[(d0+k)*4];
    w[k][0]=c4.x; w[k][1]=c4.y; w[k][2]=c4.z; w[k][3]=c4.w;
  }
  const _Float16* base = xin + ((size_t)b*LEN)*DIN + d0;
  #pragma unroll
  for(int j=0;j<4;j++){
    int ls = l - 3 + j;
    if(ls >= 0){
      half8 xv = *(const half8*)&base[(size_t)ls*DIN];
      #pragma unroll
      for(int k=0;k<8;k++) acc[k] += (float)xv[k] * w[k][j];
    }
  }
  short8 o;
  #pragma unroll
  for(int k=0;k<8;k++){
    float v = acc[k] * sigmoidf_(acc[k]);
    o[k] = (short)f2bf(v);
  }
  *(short8*)&u[((size_t)b*LEN + l)*DIN + d0] = o;
}

// ---------------- GEMM2 MFMA: u[16384][1024] x Wxpb[64][1024] -> dbl fp32 [16384][64] ----------------
__global__ __launch_bounds__(256) void gemm2_mfma(const ushort_t* __restrict__ A,
    const ushort_t* __restrict__ Bw, float* __restrict__ dbl){
  __shared__ __align__(16) ushort_t As[128*64];
  __shared__ __align__(16) ushort_t Bs[64*64];
  int tid = threadIdx.x;
  int wave = tid >> 6, lane = tid & 63;
  int m0 = blockIdx.x * 128;
  int wm = (wave >> 1) * 64, wn = (wave & 1) * 32;
  int lm = lane & 15;
  int lk = lane >> 4;
  f32x4 zero4 = {0.f,0.f,0.f,0.f};
  f32x4 acc[4][2];
  #pragma unroll
  for(int i=0;i<4;i++){ acc[i][0] = zero4; acc[i][1] = zero4; }
  for(int k0=0; k0<1024; k0+=64){
    __syncthreads();
    #pragma unroll
    for(int i=0;i<4;i++){
      int c = i*256 + tid;
      int r = c >> 3, kc = c & 7;
      gl2lds16(&A[(size_t)(m0 + r)*1024 + k0 + kc*8], &As[c*8]);
    }
    #pragma unroll
    for(int i=0;i<2;i++){
      int c = i*256 + tid;
      int r = c >> 3, kc = c & 7;
      gl2lds16(&Bw[(size_t)r*1024 + k0 + kc*8], &Bs[c*8]);
    }
    __syncthreads();
    #pragma unroll
    for(int kk=0; kk<64; kk+=32){
      short8 af[4], bf[2];
      #pragma unroll
      for(int i=0;i<4;i++) af[i] = *(const short8*)&As[(wm + i*16 + lm)*64 + kk + lk*8];
      #pragma unroll
      for(int j=0;j<2;j++) bf[j] = *(const short8*)&Bs[(wn + j*16 + lm)*64 + kk + lk*8];
      #pragma unroll
      for(int i=0;i<4;i++)
        #pragma unroll
        for(int j=0;j<2;j++)
          acc[i][j] = __builtin_amdgcn_mfma_f32_16x16x32_bf16(af[i], bf[j], acc[i][j], 0, 0, 0);
    }
  }
  #pragma unroll
  for(int i=0;i<4;i++)
    #pragma unroll
    for(int j=0;j<2;j++)
      #pragma unroll
      for(int r=0;r<4;r++){
        int m = m0 + wm + i*16 + lk*4 + r;
        int n = wn + j*16 + lm;
        dbl[(size_t)m*64 + n] = acc[i][j][r];
      }
}

// ---------------- deltag: dv[m,d] = softplus(dbl[m,0:32]·Wdt[d,:]+bdt[d]) -> fp16 ----------------
__global__ __launch_bounds__(256,4) void deltag_k(const float* __restrict__ dbl,
    const float* __restrict__ Wdt, const float* __restrict__ bdt,
    _Float16* __restrict__ dF){
  __shared__ __align__(16) float dts[64*32];
  int bid = blockIdx.x;              // 256 m-tiles x 4 d-tiles = 1024
  int d0 = (bid & 3) * 256;
  int m0 = (bid >> 2) * 64;
  int tid = threadIdx.x;
  const f32x4* src4 = (const f32x4*)(dbl + (size_t)m0*64);
  f32x4* dst4 = (f32x4*)dts;
  for(int i=tid; i<64*8; i+=256){
    int row = i >> 3, q = i & 7;
    dst4[i] = src4[row*16 + q];
  }
  int d = d0 + tid;
  float w[32];
  #pragma unroll
  for(int k=0;k<32;k+=4){
    float4 t4 = *(const float4*)&Wdt[d*32+k];
    w[k]=t4.x; w[k+1]=t4.y; w[k+2]=t4.z; w[k+3]=t4.w;
  }
  float bd = bdt[d];
  __syncthreads();
  for(int m=0;m<64;m++){
    const float* row = dts + m*32;
    float dtv = bd;
    #pragma unroll
    for(int k=0;k<32;k+=4){
      f32x4 q = *(const f32x4*)&row[k];
      dtv += q.x*w[k] + q.y*w[k+1] + q.z*w[k+2] + q.w*w[k+3];
    }
    float dv = dtv > 15.f ? dtv : __logf(1.f + __expf(dtv));
    dF[(size_t)(m0+m)*DIN + d] = (_Float16)dv;
  }
}

// ---------------- scan phase A: per-chunk local end state + cumD ----------------
__global__ __launch_bounds__(256,4) void scanA_k(const ushort_t* __restrict__ u,
    const float* __restrict__ dbl, const float* __restrict__ Alog,
    const _Float16* __restrict__ dF,
    float* __restrict__ E, float* __restrict__ cum){
  __shared__ __align__(16) float dch[CHL*16];   // B cols
  int bid = blockIdx.x;            // NCH*4*Bsz = 1024
  int c = bid & (NCH-1);
  int dblk = (bid >> 6) & 3;
  int b = bid >> 8;
  int d = dblk*256 + threadIdx.x;
  const f32x4* src = (const f32x4*)(dbl + ((size_t)b*LEN + c*CHL)*64);
  f32x4* dst4 = (f32x4*)dch;
  for(int i=threadIdx.x; i<CHL*4; i+=256){
    int t = i >> 2, q = i & 3;
    dst4[i] = src[t*16 + 8 + q];
  }
  float nA[DST];
  bool fast = load_nA(Alog, d, nA);
  float Es[DST];
  #pragma unroll
  for(int s=0;s<DST;s++) Es[s] = 0.f;
  float cumD = 0.f;
  __syncthreads();
  const ushort_t*  uu = u  + ((size_t)b*LEN + c*CHL)*DIN + d;
  const _Float16*  pd = dF + ((size_t)b*LEN + c*CHL)*DIN + d;
  if(fast){
    for(int t=0;t<CHL;++t){
      float dv = (float)pd[(size_t)t*DIN];
      float uv = bf2f(uu[(size_t)t*DIN]);
      float du = dv*uv;
      cumD += dv;
      float a1 = __expf(-dv);
      float av[DST];
      POW_CHAIN(av, a1);
      const f32x4* r4 = (const f32x4*)(dch + t*16);
      f32x4 B0=r4[0], B1=r4[1], B2=r4[2], B3=r4[3];
      Es[0]=av[0]*Es[0]+du*B0.x;  Es[1]=av[1]*Es[1]+du*B0.y;
      Es[2]=av[2]*Es[2]+du*B0.z;  Es[3]=av[3]*Es[3]+du*B0.w;
      Es[4]=av[4]*Es[4]+du*B1.x;  Es[5]=av[5]*Es[5]+du*B1.y;
      Es[6]=av[6]*Es[6]+du*B1.z;  Es[7]=av[7]*Es[7]+du*B1.w;
      Es[8]=av[8]*Es[8]+du*B2.x;  Es[9]=av[9]*Es[9]+du*B2.y;
      Es[10]=av[10]*Es[10]+du*B2.z; Es[11]=av[11]*Es[11]+du*B2.w;
      Es[12]=av[12]*Es[12]+du*B3.x; Es[13]=av[13]*Es[13]+du*B3.y;
      Es[14]=av[14]*Es[14]+du*B3.z; Es[15]=av[15]*Es[15]+du*B3.w;
    }
  } else {
    for(int t=0;t<CHL;++t){
      float dv = (float)pd[(size_t)t*DIN];
      float uv = bf2f(uu[(size_t)t*DIN]);
      float du = dv*uv;
      cumD += dv;
      const float* row = dch + t*16;
      #pragma unroll
      for(int s=0;s<DST;s++){
        float a = __expf(dv*nA[s]);
        Es[s] = a*Es[s] + du*row[s];
      }
    }
  }
  size_t o = (size_t)(b*NCH + c)*DST*DIN + d;
  #pragma unroll
  for(int s=0;s<DST;s++) E[o + (size_t)s*DIN] = Es[s];
  cum[(size_t)(b*NCH + c)*DIN + d] = cumD;
}

// ---------------- scan phase B: combine chunk boundaries; Hs in-place over E ----------------
__global__ __launch_bounds__(256) void scanB_k(const float* __restrict__ cum,
    const float* __restrict__ Alog, float* __restrict__ E){
  int g = blockIdx.x*256 + threadIdx.x;   // 65536 = Bsz*DST*DIN
  int d = g & 1023;
  int s = (g >> 10) & 15;
  int b = g >> 14;
  float v = -__expf(Alog[d*DST + s]);
  float tgt = -(float)(s+1);
  float nA = (fabsf(v - tgt) < 1e-4f*(float)(s+1)) ? tgt : v;
  float h = 0.f;
  for(int c=0;c<NCH;c++){
    float p = __expf(cum[(size_t)(b*NCH + c)*DIN + d] * nA);
    size_t o = (size_t)((b*NCH + c)*DST + s)*DIN + d;
    float e = E[o];
    E[o] = h;
    h = p*h + e;
  }
}

// ---------------- scan phase C: replay, y=(scan+u*D)*sz, y bf16 over u ----------------
__global__ __launch_bounds__(256,4) void scanC_k(ushort_t* __restrict__ u,
    const float* __restrict__ dbl, const float* __restrict__ Alog,
    const float* __restrict__ Hs, const float* __restrict__ Dp, const ushort_t* __restrict__ sz,
    const _Float16* __restrict__ dF){
  __shared__ __align__(16) float dch[CHL*32];   // B,C cols
  int bid = blockIdx.x;
  int c = bid & (NCH-1);
  int dblk = (bid >> 6) & 3;
  int b = bid >> 8;
  int d = dblk*256 + threadIdx.x;
  const f32x4* src = (const f32x4*)(dbl + ((size_t)b*LEN + c*CHL)*64);
  f32x4* dst4 = (f32x4*)dch;
  for(int i=threadIdx.x; i<CHL*8; i+=256){
    int t = i >> 3, q = i & 7;
    dst4[i] = src[t*16 + 8 + q];
  }
  float nA[DST];
  bool fast = load_nA(Alog, d, nA);
  float h[DST];
  size_t ho = (size_t)(b*NCH + c)*DST*DIN + d;
  #pragma unroll
  for(int s=0;s<DST;s++) h[s] = Hs[ho + (size_t)s*DIN];
  float Dv = Dp[d];
  __syncthreads();
  ushort_t* uu = u + ((size_t)b*LEN + c*CHL)*DIN + d;
  const ushort_t* zz = sz + ((size_t)b*LEN + c*CHL)*DIN + d;
  const _Float16* pd = dF + ((size_t)b*LEN + c*CHL)*DIN + d;
  if(fast){
    for(int t=0;t<CHL;++t){
      float dv = (float)pd[(size_t)t*DIN];
      float uv = bf2f(uu[(size_t)t*DIN]);
      float du = dv*uv;
      float a1 = __expf(-dv);
      float av[DST];
      POW_CHAIN(av, a1);
      const f32x4* r4 = (const f32x4*)(dch + t*32);
      f32x4 B0=r4[0], B1=r4[1], B2=r4[2], B3=r4[3];
      f32x4 C0=r4[4], C1=r4[5], C2=r4[6], C3=r4[7];
      float y0, y1, y2, y3;
      h[0]=av[0]*h[0]+du*B0.x;  h[1]=av[1]*h[1]+du*B0.y;
      h[2]=av[2]*h[2]+du*B0.z;  h[3]=av[3]*h[3]+du*B0.w;
      y0 = h[0]*C0.x + h[1]*C0.y; y1 = h[2]*C0.z + h[3]*C0.w;
      h[4]=av[4]*h[4]+du*B1.x;  h[5]=av[5]*h[5]+du*B1.y;
      h[6]=av[6]*h[6]+du*B1.z;  h[7]=av[7]*h[7]+du*B1.w;
      y2 = h[4]*C1.x + h[5]*C1.y; y3 = h[6]*C1.z + h[7]*C1.w;
      h[8]=av[8]*h[8]+du*B2.x;  h[9]=av[9]*h[9]+du*B2.y;
      h[10]=av[10]*h[10]+du*B2.z; h[11]=av[11]*h[11]+du*B2.w;
      y0 += h[8]*C2.x + h[9]*C2.y; y1 += h[10]*C2.z + h[11]*C2.w;
      h[12]=av[12]*h[12]+du*B3.x; h[13]=av[13]*h[13]+du*B3.y;
      h[14]=av[14]*h[14]+du*B3.z; h[15]=av[15]*h[15]+du*B3.w;
      y2 += h[12]*C3.x + h[13]*C3.y; y3 += h[14]*C3.z + h[15]*C3.w;
      float y = (y0+y1) + (y2+y3) + uv*Dv;
      y *= bf2f(zz[(size_t)t*DIN]);
      uu[(size_t)t*DIN] = f2bf(y);
    }
  } else {
    for(int t=0;t<CHL;++t){
      float dv = (float)pd[(size_t)t*DIN];
      float uv = bf2f(uu[(size_t)t*DIN]);
      float du = dv*uv;
      const float* row = dch + t*32;
      float y = 0.f;
      #pragma unroll
      for(int s=0;s<DST;s++){
        float a = __expf(dv*nA[s]);
        h[s] = a*h[s] + du*row[s];
        y += h[s]*row[16+s];
      }
      y += uv*Dv;
      y *= bf2f(zz[(size_t)t*DIN]);
      uu[(size_t)t*DIN] = f2bf(y);
    }
  }
}

// ---------------- GEMM4 MFMA: y[16384][1024] x Woutb[512][1024] -> out[b][n][l] ----------------
__global__ __launch_bounds__(256) void gemm4_mfma(const ushort_t* __restrict__ A,
    const ushort_t* __restrict__ Bw, float* __restrict__ out){
  __shared__ __align__(16) ushort_t smem[2*128*64];   // As | Bs ; epilogue reuses as float
  ushort_t* As = smem;
  ushort_t* Bs = smem + 128*64;
  int tid = threadIdx.x;
  int wave = tid >> 6, lane = tid & 63;
  int n0 = blockIdx.x * 128;       // N=512 -> 4
  int m0 = blockIdx.y * 128;
  int wm = (wave >> 1) * 64, wn = (wave & 1) * 64;
  int lm = lane & 15;
  int lk = lane >> 4;
  f32x4 zero4 = {0.f,0.f,0.f,0.f};
  f32x4 acc[4][4];
  #pragma unroll
  for(int i=0;i<4;i++)
    #pragma unroll
    for(int j=0;j<4;j++) acc[i][j] = zero4;
  for(int k0=0; k0<1024; k0+=64){
    __syncthreads();
    #pragma unroll
    for(int i=0;i<4;i++){
      int c = i*256 + tid;
      int r = c >> 3, kc = c & 7;
      gl2lds16(&A [(size_t)(m0 + r)*1024 + k0 + kc*8], &As[c*8]);
      gl2lds16(&Bw[(size_t)(n0 + r)*1024 + k0 + kc*8], &Bs[c*8]);
    }
    __syncthreads();
    #pragma unroll
    for(int kk=0; kk<64; kk+=32){
      short8 af[4], bf[4];
      #pragma unroll
      for(int i=0;i<4;i++){
        af[i] = *(const short8*)&As[(wm + i*16 + lm)*64 + kk + lk*8];
        bf[i] = *(const short8*)&Bs[(wn + i*16 + lm)*64 + kk + lk*8];
      }
      #pragma unroll
      for(int i=0;i<4;i++)
        #pragma unroll
        for(int j=0;j<4;j++)
          acc[i][j] = __builtin_amdgcn_mfma_f32_16x16x32_bf16(af[i], bf[j], acc[i][j], 0, 0, 0);
    }
  }
  // epilogue: LDS transpose, 32-n groups, coalesced float4 stores along l(=m)
  float* T = (float*)smem;               // [32][132] fp32
  int b = m0 >> 12, l0 = m0 & 4095;
  for(int g=0; g<4; ++g){
    __syncthreads();
    if((g >> 1) == (wave & 1)){
      int jg = g & 1;
      #pragma unroll
      for(int j2=0;j2<2;j2++){
        int j = jg*2 + j2;
        #pragma unroll
        for(int i=0;i<4;i++)
          #pragma unroll
          for(int r=0;r<4;r++){
            int ml = wm + i*16 + lk*4 + r;
            int nl = wn + j*16 + lm - g*32;
            T[nl*132 + ml] = acc[i][j][r];
          }
      }
    }
    __syncthreads();
    int nl = tid >> 3, seg = tid & 7;
    float* dst = &out[((size_t)b*DIM + n0 + g*32 + nl)*LEN + l0 + seg*16];
    #pragma unroll
    for(int k=0;k<4;k++){
      float4 v = *(const float4*)&T[nl*132 + seg*16 + k*4];
      *(float4*)&dst[k*4] = v;
    }
  }
}

extern "C" void kernel_launch(void* const* d_in, const int* in_sizes, int n_in,
                              void* d_out, int out_size, void* d_ws, size_t ws_size,
                              hipStream_t stream) {
  const float* x    = (const float*)d_in[0];
  const float* lnw  = (const float*)d_in[1];
  const float* lnb  = (const float*)d_in[2];
  const float* Win  = (const float*)d_in[3];
  const float* cw   = (const float*)d_in[4];
  const float* cb   = (const float*)d_in[5];
  const float* Wxp  = (const float*)d_in[6];
  const float* Wdt  = (const float*)d_in[7];
  const float* bdt  = (const float*)d_in[8];
  const float* Alog = (const float*)d_in[9];
  const float* Dp   = (const float*)d_in[10];
  const float* Wout = (const float*)d_in[11];
  float* out = (float*)d_out;
  float* ws  = (float*)d_ws;

  // workspace layout (float-slot offsets), total 147.25 MiB — no overlapping live ranges:
  //   region1 [32768, 32768+16777216):
  //     xin fp16 [  +0, +8388608)  (live gemm1..conv)
  //     dF  fp16 [  +0, +8388608)  (live deltag..scanC; disjoint lifetime from xin)
  //     E   fp32 [+8388608, +12582912)
  //     cum      [+12582912, +12845056)
  float*    mu   = ws;                          // 16384
  float*    rs   = ws + 16384;                  // 16384
  _Float16* xin  = (_Float16*)(ws + 32768);     // fp16, 16,777,216 halves
  _Float16* dF   = (_Float16*)(ws + 32768);     // same region, disjoint lifetime
  float*    E    = ws + 32768 + 8388608;        // 4,194,304 fl (Hs in-place)
  float*    cum  = ws + 32768 + 12582912;       // 262,144 fl
  ushort_t* sz   = (ushort_t*)(ws + 32768 + 16777216);            // bf16 16,777,216
  ushort_t* u    = (ushort_t*)(ws + 32768 + 16777216 + 8388608);  // bf16 16,777,216 (y overwrites)
  ushort_t* xnT  = (ushort_t*)(ws + 32768 + 16777216 + 16777216); // bf16 8,388,608
  float*    dbl  = (float*)xnT;                 // alias after gemm1: 1,048,576 fp32
  ushort_t* Winb = (ushort_t*)(ws + 32768 + 16777216 + 16777216 + 4194304);
  ushort_t* Woutb= Winb + 1048576;
  ushort_t* Wxpb = Woutb + 524288;

  hipLaunchKernelGGL(ln_stats_k, dim3(256),     dim3(256), 0, stream, x, mu, rs);
  hipLaunchKernelGGL(wcvt_k,     dim3(6400),    dim3(256), 0, stream, Win, Wout, Wxp, Winb, Woutb, Wxpb);
  hipLaunchKernelGGL(xnt_k,      dim3(2048),    dim3(256), 0, stream, x, mu, rs, lnw, lnb, xnT);
  hipLaunchKernelGGL(gemm1_mfma, dim3(16,128),  dim3(256), 0, stream, xnT, Winb, xin, sz);
  hipLaunchKernelGGL(conv_silu_k,dim3(8192),    dim3(256), 0, stream, xin, cw, cb, u);
  hipLaunchKernelGGL(gemm2_mfma, dim3(128),     dim3(256), 0, stream, u, Wxpb, dbl);
  hipLaunchKernelGGL(deltag_k,   dim3(1024),    dim3(256), 0, stream, dbl, Wdt, bdt, dF);
  hipLaunchKernelGGL(scanA_k,    dim3(1024),    dim3(256), 0, stream, u, dbl, Alog, dF, E, cum);
  hipLaunchKernelGGL(scanB_k,    dim3(256),     dim3(256), 0, stream, cum, Alog, E);
  hipLaunchKernelGGL(scanC_k,    dim3(1024),    dim3(256), 0, stream, u, dbl, Alog, E, Dp, sz, dF);
  hipLaunchKernelGGL(gemm4_mfma, dim3(4,128),   dim3(256), 0, stream, u, Woutb, out);
}

// Round 8
// 408.975 us; speedup vs baseline: 2.7298x; 1.0447x over previous
//
#include <hip/hip_runtime.h>
#include <math.h>

#define Bsz 4
#define DIM 512
#define LEN 4096
#define DST 16
#define DIN 1024
#define NCH 64    // chunks over L
#define CHL 64    // chunk length
#define LDP 72    // padded LDS row stride (ushorts), 144B: 16B-aligned, 2-way-max conflicts

typedef unsigned short ushort_t;
typedef unsigned int uint_t;
typedef __attribute__((ext_vector_type(8))) short short8;          // 8 bf16 (4 VGPRs)
typedef __attribute__((ext_vector_type(8))) unsigned short ushort8;
typedef __attribute__((ext_vector_type(8))) _Float16 half8;        // 8 fp16
typedef __attribute__((ext_vector_type(4))) float f32x4;

__device__ __forceinline__ float sigmoidf_(float x){ return 1.0f/(1.0f+__expf(-x)); }
__device__ __forceinline__ float bf2f(ushort_t u){ return __uint_as_float(((uint_t)u) << 16); }
__device__ __forceinline__ ushort_t f2bf(float f){
  uint_t x = __float_as_uint(f);
  uint_t r = (x + 0x7FFFu + ((x >> 16) & 1u)) >> 16;
  return (ushort_t)r;
}
__device__ __forceinline__ ushort_t f2h_bits(float f){
  _Float16 h = (_Float16)f;
  union { _Float16 h; ushort_t u; } v; v.h = h; return v.u;
}
__device__ __forceinline__ void gl2lds16(const void* g, void* l){
  __builtin_amdgcn_global_load_lds((const __attribute__((address_space(1))) void*)g,
                                   (__attribute__((address_space(3))) void*)l, 16, 0, 0);
}
// a^1..a^16 from a1=exp(-dv), log-depth
#define POW_CHAIN(av, a1) \
  { float a2=a1*a1, a4=a2*a2, a8=a4*a4; \
    av[0]=a1; av[1]=a2; av[2]=a2*a1; av[3]=a4; \
    av[4]=a4*a1; av[5]=a4*a2; av[6]=a4*av[2]; av[7]=a8; \
    av[8]=a8*a1; av[9]=a8*a2; av[10]=a8*av[2]; av[11]=a8*a4; \
    av[12]=a8*av[4]; av[13]=a8*av[5]; av[14]=a8*av[6]; av[15]=a8*a8; }

__device__ __forceinline__ bool load_nA(const float* Alog, int d, float* nA){
  bool fast = true;
  #pragma unroll
  for(int s=0;s<DST;s++){
    float v = -__expf(Alog[d*DST+s]);
    float tgt = -(float)(s+1);
    if(fabsf(v - tgt) < 1e-4f*(float)(s+1)) v = tgt;
    else fast = false;
    nA[s] = v;
  }
  return fast;
}

// ---------------- LayerNorm stats ----------------
__global__ __launch_bounds__(256) void ln_stats_k(const float* __restrict__ x,
                                                  float* __restrict__ mu, float* __restrict__ rs){
  int bid = blockIdx.x;
  int b = bid >> 6;
  int lg = bid & 63;
  int lane = threadIdx.x & 63;
  int g = threadIdx.x >> 6;
  int l = lg*64 + lane;
  const float* xb = x + (size_t)b*DIM*LEN + l;
  float s = 0.f, sq = 0.f;
  for(int d = g*128; d < g*128 + 128; ++d){
    float v = xb[(size_t)d*LEN];
    s += v; sq += v*v;
  }
  __shared__ float rsum[4][64], rsq[4][64];
  rsum[g][lane] = s; rsq[g][lane] = sq;
  __syncthreads();
  if(threadIdx.x < 64){
    float ts = 0.f, tq = 0.f;
    for(int gg=0; gg<4; ++gg){ ts += rsum[gg][lane]; tq += rsq[gg][lane]; }
    float m = ts * (1.0f/DIM);
    float var = tq * (1.0f/DIM) - m*m;
    mu[b*LEN + l] = m;
    rs[b*LEN + l] = rsqrtf(var + 1e-5f);
  }
}

// ---------------- weights -> bf16 ----------------
__global__ __launch_bounds__(256) void wcvt_k(const float* __restrict__ Win,
    const float* __restrict__ Wout, const float* __restrict__ Wxp,
    ushort_t* __restrict__ Winb, ushort_t* __restrict__ Woutb, ushort_t* __restrict__ Wxpb){
  int i = blockIdx.x*256 + threadIdx.x;   // 1,638,400 total
  if(i < 1048576) Winb[i] = f2bf(Win[i]);
  else if(i < 1572864) Woutb[i-1048576] = f2bf(Wout[i-1048576]);
  else if(i < 1638400) Wxpb[i-1572864] = f2bf(Wxp[i-1572864]);
}

// ---------------- LN apply + transpose -> xnT bf16 [B*L][512] ----------------
__global__ __launch_bounds__(256) void xnt_k(const float* __restrict__ x,
    const float* __restrict__ mu, const float* __restrict__ rs,
    const float* __restrict__ lnw, const float* __restrict__ lnb, ushort_t* __restrict__ xnT){
  __shared__ ushort_t t[64][72];
  int bid = blockIdx.x;              // 4 * 8 * 64 = 2048
  int lt = bid & 63;
  int dt_ = (bid >> 6) & 7;
  int b = bid >> 9;
  int l0 = lt*64, d0 = dt_*64;
  int ll = threadIdx.x & 63;
  int dq = threadIdx.x >> 6;
  float mul_ = mu[b*LEN + l0 + ll], rsl = rs[b*LEN + l0 + ll];
  const float* xb = x + (size_t)b*DIM*LEN;
  #pragma unroll
  for(int i=0;i<16;i++){
    int d = d0 + dq*16 + i;
    float v = xb[(size_t)d*LEN + l0 + ll];
    t[ll][dq*16 + i] = f2bf((v - mul_)*rsl*lnw[d] + lnb[d]);
  }
  __syncthreads();
  int lr = threadIdx.x >> 2, seg = threadIdx.x & 3;
  ushort_t* dst = &xnT[(size_t)(b*LEN + l0 + lr)*DIM + d0 + seg*16];
  #pragma unroll
  for(int k=0;k<4;k++){
    ushort4 v = *(const ushort4*)&t[lr][seg*16 + k*4];
    *(ushort4*)&dst[k*4] = v;
  }
}

// ---------------- GEMM1 MFMA v2: padded LDS + reg double-buffer + vector epilogue ----------------
// xnT[16384][512] x Winb[2048][512] -> xin fp16 (n<1024) / sz bf16 (n>=1024)
__global__ __launch_bounds__(256) void gemm1_mfma(const ushort_t* __restrict__ A,
    const ushort_t* __restrict__ Bw, _Float16* __restrict__ xin, ushort_t* __restrict__ sz){
  __shared__ __align__(16) ushort_t smem[2*128*LDP];   // 36,864 B
  ushort_t* As = smem;
  ushort_t* Bs = smem + 128*LDP;
  int tid = threadIdx.x;
  int wave = tid >> 6, lane = tid & 63;
  int n0 = blockIdx.x * 128;
  int m0 = blockIdx.y * 128;
  int wm = (wave >> 1) * 64, wn = (wave & 1) * 64;
  int lm = lane & 15;
  int lk = lane >> 4;
  f32x4 zero4 = {0.f,0.f,0.f,0.f};
  f32x4 acc[4][4];
  #pragma unroll
  for(int i=0;i<4;i++)
    #pragma unroll
    for(int j=0;j<4;j++) acc[i][j] = zero4;
  // prefetch k0=0
  ushort8 ar[4], br[4];
  #pragma unroll
  for(int i=0;i<4;i++){
    int c = i*256 + tid, r = c >> 3, kc = c & 7;
    ar[i] = *(const ushort8*)&A [(size_t)(m0 + r)*512 + kc*8];
    br[i] = *(const ushort8*)&Bw[(size_t)(n0 + r)*512 + kc*8];
  }
  for(int k0=0; k0<512; k0+=64){
    __syncthreads();
    #pragma unroll
    for(int i=0;i<4;i++){
      int c = i*256 + tid, r = c >> 3, kc = c & 7;
      *(ushort8*)&As[r*LDP + kc*8] = ar[i];
      *(ushort8*)&Bs[r*LDP + kc*8] = br[i];
    }
    if(k0 + 64 < 512){
      #pragma unroll
      for(int i=0;i<4;i++){
        int c = i*256 + tid, r = c >> 3, kc = c & 7;
        ar[i] = *(const ushort8*)&A [(size_t)(m0 + r)*512 + k0 + 64 + kc*8];
        br[i] = *(const ushort8*)&Bw[(size_t)(n0 + r)*512 + k0 + 64 + kc*8];
      }
    }
    __syncthreads();
    #pragma unroll
    for(int kk=0; kk<64; kk+=32){
      short8 af[4], bf[4];
      #pragma unroll
      for(int i=0;i<4;i++){
        af[i] = *(const short8*)&As[(wm + i*16 + lm)*LDP + kk + lk*8];
        bf[i] = *(const short8*)&Bs[(wn + i*16 + lm)*LDP + kk + lk*8];
      }
      #pragma unroll
      for(int i=0;i<4;i++)
        #pragma unroll
        for(int j=0;j<4;j++)
          acc[i][j] = __builtin_amdgcn_mfma_f32_16x16x32_bf16(af[i], bf[j], acc[i][j], 0, 0, 0);
    }
  }
  // epilogue: LDS transpose (ushort [128][136]) + coalesced 16B stores
  __syncthreads();
  ushort_t* T = smem;                      // 128*136*2 = 34,816 B <= 36,864
  bool is_z = (n0 >= 1024);
  #pragma unroll
  for(int i=0;i<4;i++)
    #pragma unroll
    for(int j=0;j<4;j++)
      #pragma unroll
      for(int r=0;r<4;r++){
        int ml = wm + i*16 + lk*4 + r;
        int nl = wn + j*16 + lm;
        float v = acc[i][j][r];
        T[ml*136 + nl] = is_z ? f2bf(v * sigmoidf_(v)) : f2h_bits(v);
      }
  __syncthreads();
  int rr = tid >> 4, cc = (tid & 15)*8;
  #pragma unroll
  for(int p=0;p<8;p++){
    int row = p*16 + rr;
    ushort8 v = *(const ushort8*)&T[row*136 + cc];
    if(!is_z) *(ushort8*)((ushort_t*)xin + (size_t)(m0+row)*DIN + n0 + cc) = v;
    else      *(ushort8*)&sz[(size_t)(m0+row)*DIN + (n0-1024) + cc] = v;
  }
}

// ---------------- conv1d + SiLU -> u bf16 (8 d per thread, vectorized) ----------------
__global__ __launch_bounds__(256) void conv_silu_k(const _Float16* __restrict__ xin,
    const float* __restrict__ cw, const float* __restrict__ cb, ushort_t* __restrict__ u){
  int idx = blockIdx.x*256 + threadIdx.x;   // 2,097,152 threads: (b,l,dgrp)
  int dg = idx & 127;
  int l  = (idx >> 7) & 4095;
  int b  = idx >> 19;
  int d0 = dg*8;
  float acc[8];
  #pragma unroll
  for(int k=0;k<8;k+=4){
    float4 c4 = *(const float4*)&cb[d0+k];
    acc[k]=c4.x; acc[k+1]=c4.y; acc[k+2]=c4.z; acc[k+3]=c4.w;
  }
  float w[8][4];
  #pragma unroll
  for(int k=0;k<8;k++){
    float4 c4 = *(const float4*)&cw[(d0+k)*4];
    w[k][0]=c4.x; w[k][1]=c4.y; w[k][2]=c4.z; w[k][3]=c4.w;
  }
  const _Float16* base = xin + ((size_t)b*LEN)*DIN + d0;
  #pragma unroll
  for(int j=0;j<4;j++){
    int ls = l - 3 + j;
    if(ls >= 0){
      half8 xv = *(const half8*)&base[(size_t)ls*DIN];
      #pragma unroll
      for(int k=0;k<8;k++) acc[k] += (float)xv[k] * w[k][j];
    }
  }
  short8 o;
  #pragma unroll
  for(int k=0;k<8;k++){
    float v = acc[k] * sigmoidf_(acc[k]);
    o[k] = (short)f2bf(v);
  }
  *(short8*)&u[((size_t)b*LEN + l)*DIN + d0] = o;
}

// ---------------- GEMM2 MFMA: u[16384][1024] x Wxpb[64][1024] -> dbl fp32 [16384][64] ----------------
__global__ __launch_bounds__(256) void gemm2_mfma(const ushort_t* __restrict__ A,
    const ushort_t* __restrict__ Bw, float* __restrict__ dbl){
  __shared__ __align__(16) ushort_t As[128*64];
  __shared__ __align__(16) ushort_t Bs[64*64];
  int tid = threadIdx.x;
  int wave = tid >> 6, lane = tid & 63;
  int m0 = blockIdx.x * 128;
  int wm = (wave >> 1) * 64, wn = (wave & 1) * 32;
  int lm = lane & 15;
  int lk = lane >> 4;
  f32x4 zero4 = {0.f,0.f,0.f,0.f};
  f32x4 acc[4][2];
  #pragma unroll
  for(int i=0;i<4;i++){ acc[i][0] = zero4; acc[i][1] = zero4; }
  for(int k0=0; k0<1024; k0+=64){
    __syncthreads();
    #pragma unroll
    for(int i=0;i<4;i++){
      int c = i*256 + tid;
      int r = c >> 3, kc = c & 7;
      gl2lds16(&A[(size_t)(m0 + r)*1024 + k0 + kc*8], &As[c*8]);
    }
    #pragma unroll
    for(int i=0;i<2;i++){
      int c = i*256 + tid;
      int r = c >> 3, kc = c & 7;
      gl2lds16(&Bw[(size_t)r*1024 + k0 + kc*8], &Bs[c*8]);
    }
    __syncthreads();
    #pragma unroll
    for(int kk=0; kk<64; kk+=32){
      short8 af[4], bf[2];
      #pragma unroll
      for(int i=0;i<4;i++) af[i] = *(const short8*)&As[(wm + i*16 + lm)*64 + kk + lk*8];
      #pragma unroll
      for(int j=0;j<2;j++) bf[j] = *(const short8*)&Bs[(wn + j*16 + lm)*64 + kk + lk*8];
      #pragma unroll
      for(int i=0;i<4;i++)
        #pragma unroll
        for(int j=0;j<2;j++)
          acc[i][j] = __builtin_amdgcn_mfma_f32_16x16x32_bf16(af[i], bf[j], acc[i][j], 0, 0, 0);
    }
  }
  #pragma unroll
  for(int i=0;i<4;i++)
    #pragma unroll
    for(int j=0;j<2;j++)
      #pragma unroll
      for(int r=0;r<4;r++){
        int m = m0 + wm + i*16 + lk*4 + r;
        int n = wn + j*16 + lm;
        dbl[(size_t)m*64 + n] = acc[i][j][r];
      }
}

// ---------------- deltag: dv[m,d] = softplus(dbl[m,0:32]·Wdt[d,:]+bdt[d]) -> fp16 ----------------
__global__ __launch_bounds__(256,4) void deltag_k(const float* __restrict__ dbl,
    const float* __restrict__ Wdt, const float* __restrict__ bdt,
    _Float16* __restrict__ dF){
  __shared__ __align__(16) float dts[64*32];
  int bid = blockIdx.x;              // 256 m-tiles x 4 d-tiles = 1024
  int d0 = (bid & 3) * 256;
  int m0 = (bid >> 2) * 64;
  int tid = threadIdx.x;
  const f32x4* src4 = (const f32x4*)(dbl + (size_t)m0*64);
  f32x4* dst4 = (f32x4*)dts;
  for(int i=tid; i<64*8; i+=256){
    int row = i >> 3, q = i & 7;
    dst4[i] = src4[row*16 + q];
  }
  int d = d0 + tid;
  float w[32];
  #pragma unroll
  for(int k=0;k<32;k+=4){
    float4 t4 = *(const float4*)&Wdt[d*32+k];
    w[k]=t4.x; w[k+1]=t4.y; w[k+2]=t4.z; w[k+3]=t4.w;
  }
  float bd = bdt[d];
  __syncthreads();
  for(int m=0;m<64;m++){
    const float* row = dts + m*32;
    float dtv = bd;
    #pragma unroll
    for(int k=0;k<32;k+=4){
      f32x4 q = *(const f32x4*)&row[k];
      dtv += q.x*w[k] + q.y*w[k+1] + q.z*w[k+2] + q.w*w[k+3];
    }
    float dv = dtv > 15.f ? dtv : __logf(1.f + __expf(dtv));
    dF[(size_t)(m0+m)*DIN + d] = (_Float16)dv;
  }
}

// ---------------- scan phase A: per-chunk local end state + cumD ----------------
__global__ __launch_bounds__(256,4) void scanA_k(const ushort_t* __restrict__ u,
    const float* __restrict__ dbl, const float* __restrict__ Alog,
    const _Float16* __restrict__ dF,
    float* __restrict__ E, float* __restrict__ cum){
  __shared__ __align__(16) float dch[CHL*16];   // B cols
  int bid = blockIdx.x;            // NCH*4*Bsz = 1024
  int c = bid & (NCH-1);
  int dblk = (bid >> 6) & 3;
  int b = bid >> 8;
  int d = dblk*256 + threadIdx.x;
  const f32x4* src = (const f32x4*)(dbl + ((size_t)b*LEN + c*CHL)*64);
  f32x4* dst4 = (f32x4*)dch;
  for(int i=threadIdx.x; i<CHL*4; i+=256){
    int t = i >> 2, q = i & 3;
    dst4[i] = src[t*16 + 8 + q];
  }
  float nA[DST];
  bool fast = load_nA(Alog, d, nA);
  float Es[DST];
  #pragma unroll
  for(int s=0;s<DST;s++) Es[s] = 0.f;
  float cumD = 0.f;
  __syncthreads();
  const ushort_t*  uu = u  + ((size_t)b*LEN + c*CHL)*DIN + d;
  const _Float16*  pd = dF + ((size_t)b*LEN + c*CHL)*DIN + d;
  if(fast){
    for(int t=0;t<CHL;++t){
      float dv = (float)pd[(size_t)t*DIN];
      float uv = bf2f(uu[(size_t)t*DIN]);
      float du = dv*uv;
      cumD += dv;
      float a1 = __expf(-dv);
      float av[DST];
      POW_CHAIN(av, a1);
      const f32x4* r4 = (const f32x4*)(dch + t*16);
      f32x4 B0=r4[0], B1=r4[1], B2=r4[2], B3=r4[3];
      Es[0]=av[0]*Es[0]+du*B0.x;  Es[1]=av[1]*Es[1]+du*B0.y;
      Es[2]=av[2]*Es[2]+du*B0.z;  Es[3]=av[3]*Es[3]+du*B0.w;
      Es[4]=av[4]*Es[4]+du*B1.x;  Es[5]=av[5]*Es[5]+du*B1.y;
      Es[6]=av[6]*Es[6]+du*B1.z;  Es[7]=av[7]*Es[7]+du*B1.w;
      Es[8]=av[8]*Es[8]+du*B2.x;  Es[9]=av[9]*Es[9]+du*B2.y;
      Es[10]=av[10]*Es[10]+du*B2.z; Es[11]=av[11]*Es[11]+du*B2.w;
      Es[12]=av[12]*Es[12]+du*B3.x; Es[13]=av[13]*Es[13]+du*B3.y;
      Es[14]=av[14]*Es[14]+du*B3.z; Es[15]=av[15]*Es[15]+du*B3.w;
    }
  } else {
    for(int t=0;t<CHL;++t){
      float dv = (float)pd[(size_t)t*DIN];
      float uv = bf2f(uu[(size_t)t*DIN]);
      float du = dv*uv;
      cumD += dv;
      const float* row = dch + t*16;
      #pragma unroll
      for(int s=0;s<DST;s++){
        float a = __expf(dv*nA[s]);
        Es[s] = a*Es[s] + du*row[s];
      }
    }
  }
  size_t o = (size_t)(b*NCH + c)*DST*DIN + d;
  #pragma unroll
  for(int s=0;s<DST;s++) E[o + (size_t)s*DIN] = Es[s];
  cum[(size_t)(b*NCH + c)*DIN + d] = cumD;
}

// ---------------- scan phase B: combine chunk boundaries; Hs in-place over E ----------------
__global__ __launch_bounds__(256) void scanB_k(const float* __restrict__ cum,
    const float* __restrict__ Alog, float* __restrict__ E){
  int g = blockIdx.x*256 + threadIdx.x;   // 65536 = Bsz*DST*DIN
  int d = g & 1023;
  int s = (g >> 10) & 15;
  int b = g >> 14;
  float v = -__expf(Alog[d*DST + s]);
  float tgt = -(float)(s+1);
  float nA = (fabsf(v - tgt) < 1e-4f*(float)(s+1)) ? tgt : v;
  float h = 0.f;
  for(int c=0;c<NCH;c++){
    float p = __expf(cum[(size_t)(b*NCH + c)*DIN + d] * nA);
    size_t o = (size_t)((b*NCH + c)*DST + s)*DIN + d;
    float e = E[o];
    E[o] = h;
    h = p*h + e;
  }
}

// ---------------- scan phase C: replay, y=(scan+u*D)*sz, y bf16 over u ----------------
__global__ __launch_bounds__(256,4) void scanC_k(ushort_t* __restrict__ u,
    const float* __restrict__ dbl, const float* __restrict__ Alog,
    const float* __restrict__ Hs, const float* __restrict__ Dp, const ushort_t* __restrict__ sz,
    const _Float16* __restrict__ dF){
  __shared__ __align__(16) float dch[CHL*32];   // B,C cols
  int bid = blockIdx.x;
  int c = bid & (NCH-1);
  int dblk = (bid >> 6) & 3;
  int b = bid >> 8;
  int d = dblk*256 + threadIdx.x;
  const f32x4* src = (const f32x4*)(dbl + ((size_t)b*LEN + c*CHL)*64);
  f32x4* dst4 = (f32x4*)dch;
  for(int i=threadIdx.x; i<CHL*8; i+=256){
    int t = i >> 3, q = i & 7;
    dst4[i] = src[t*16 + 8 + q];
  }
  float nA[DST];
  bool fast = load_nA(Alog, d, nA);
  float h[DST];
  size_t ho = (size_t)(b*NCH + c)*DST*DIN + d;
  #pragma unroll
  for(int s=0;s<DST;s++) h[s] = Hs[ho + (size_t)s*DIN];
  float Dv = Dp[d];
  __syncthreads();
  ushort_t* uu = u + ((size_t)b*LEN + c*CHL)*DIN + d;
  const ushort_t* zz = sz + ((size_t)b*LEN + c*CHL)*DIN + d;
  const _Float16* pd = dF + ((size_t)b*LEN + c*CHL)*DIN + d;
  if(fast){
    for(int t=0;t<CHL;++t){
      float dv = (float)pd[(size_t)t*DIN];
      float uv = bf2f(uu[(size_t)t*DIN]);
      float du = dv*uv;
      float a1 = __expf(-dv);
      float av[DST];
      POW_CHAIN(av, a1);
      const f32x4* r4 = (const f32x4*)(dch + t*32);
      f32x4 B0=r4[0], B1=r4[1], B2=r4[2], B3=r4[3];
      f32x4 C0=r4[4], C1=r4[5], C2=r4[6], C3=r4[7];
      float y0, y1, y2, y3;
      h[0]=av[0]*h[0]+du*B0.x;  h[1]=av[1]*h[1]+du*B0.y;
      h[2]=av[2]*h[2]+du*B0.z;  h[3]=av[3]*h[3]+du*B0.w;
      y0 = h[0]*C0.x + h[1]*C0.y; y1 = h[2]*C0.z + h[3]*C0.w;
      h[4]=av[4]*h[4]+du*B1.x;  h[5]=av[5]*h[5]+du*B1.y;
      h[6]=av[6]*h[6]+du*B1.z;  h[7]=av[7]*h[7]+du*B1.w;
      y2 = h[4]*C1.x + h[5]*C1.y; y3 = h[6]*C1.z + h[7]*C1.w;
      h[8]=av[8]*h[8]+du*B2.x;  h[9]=av[9]*h[9]+du*B2.y;
      h[10]=av[10]*h[10]+du*B2.z; h[11]=av[11]*h[11]+du*B2.w;
      y0 += h[8]*C2.x + h[9]*C2.y; y1 += h[10]*C2.z + h[11]*C2.w;
      h[12]=av[12]*h[12]+du*B3.x; h[13]=av[13]*h[13]+du*B3.y;
      h[14]=av[14]*h[14]+du*B3.z; h[15]=av[15]*h[15]+du*B3.w;
      y2 += h[12]*C3.x + h[13]*C3.y; y3 += h[14]*C3.z + h[15]*C3.w;
      float y = (y0+y1) + (y2+y3) + uv*Dv;
      y *= bf2f(zz[(size_t)t*DIN]);
      uu[(size_t)t*DIN] = f2bf(y);
    }
  } else {
    for(int t=0;t<CHL;++t){
      float dv = (float)pd[(size_t)t*DIN];
      float uv = bf2f(uu[(size_t)t*DIN]);
      float du = dv*uv;
      const float* row = dch + t*32;
      float y = 0.f;
      #pragma unroll
      for(int s=0;s<DST;s++){
        float a = __expf(dv*nA[s]);
        h[s] = a*h[s] + du*row[s];
        y += h[s]*row[16+s];
      }
      y += uv*Dv;
      y *= bf2f(zz[(size_t)t*DIN]);
      uu[(size_t)t*DIN] = f2bf(y);
    }
  }
}

// ---------------- GEMM4 MFMA v2: padded LDS + reg double-buffer; LDS-transpose epilogue ----------------
// y[16384][1024] x Woutb[512][1024] -> out[b][n][l]
__global__ __launch_bounds__(256) void gemm4_mfma(const ushort_t* __restrict__ A,
    const ushort_t* __restrict__ Bw, float* __restrict__ out){
  __shared__ __align__(16) ushort_t smem[2*128*LDP];   // 36,864 B; epilogue reuses as float
  ushort_t* As = smem;
  ushort_t* Bs = smem + 128*LDP;
  int tid = threadIdx.x;
  int wave = tid >> 6, lane = tid & 63;
  int n0 = blockIdx.x * 128;       // N=512 -> 4
  int m0 = blockIdx.y * 128;
  int wm = (wave >> 1) * 64, wn = (wave & 1) * 64;
  int lm = lane & 15;
  int lk = lane >> 4;
  f32x4 zero4 = {0.f,0.f,0.f,0.f};
  f32x4 acc[4][4];
  #pragma unroll
  for(int i=0;i<4;i++)
    #pragma unroll
    for(int j=0;j<4;j++) acc[i][j] = zero4;
  ushort8 ar[4], br[4];
  #pragma unroll
  for(int i=0;i<4;i++){
    int c = i*256 + tid, r = c >> 3, kc = c & 7;
    ar[i] = *(const ushort8*)&A [(size_t)(m0 + r)*1024 + kc*8];
    br[i] = *(const ushort8*)&Bw[(size_t)(n0 + r)*1024 + kc*8];
  }
  for(int k0=0; k0<1024; k0+=64){
    __syncthreads();
    #pragma unroll
    for(int i=0;i<4;i++){
      int c = i*256 + tid, r = c >> 3, kc = c & 7;
      *(ushort8*)&As[r*LDP + kc*8] = ar[i];
      *(ushort8*)&Bs[r*LDP + kc*8] = br[i];
    }
    if(k0 + 64 < 1024){
      #pragma unroll
      for(int i=0;i<4;i++){
        int c = i*256 + tid, r = c >> 3, kc = c & 7;
        ar[i] = *(const ushort8*)&A [(size_t)(m0 + r)*1024 + k0 + 64 + kc*8];
        br[i] = *(const ushort8*)&Bw[(size_t)(n0 + r)*1024 + k0 + 64 + kc*8];
      }
    }
    __syncthreads();
    #pragma unroll
    for(int kk=0; kk<64; kk+=32){
      short8 af[4], bf[4];
      #pragma unroll
      for(int i=0;i<4;i++){
        af[i] = *(const short8*)&As[(wm + i*16 + lm)*LDP + kk + lk*8];
        bf[i] = *(const short8*)&Bs[(wn + i*16 + lm)*LDP + kk + lk*8];
      }
      #pragma unroll
      for(int i=0;i<4;i++)
        #pragma unroll
        for(int j=0;j<4;j++)
          acc[i][j] = __builtin_amdgcn_mfma_f32_16x16x32_bf16(af[i], bf[j], acc[i][j], 0, 0, 0);
    }
  }
  // epilogue: LDS transpose, 32-n groups, coalesced float4 stores along l(=m)
  float* T = (float*)smem;               // [32][132] fp32 = 16,896 B
  int b = m0 >> 12, l0 = m0 & 4095;
  for(int g=0; g<4; ++g){
    __syncthreads();
    if((g >> 1) == (wave & 1)){
      int jg = g & 1;
      #pragma unroll
      for(int j2=0;j2<2;j2++){
        int j = jg*2 + j2;
        #pragma unroll
        for(int i=0;i<4;i++)
          #pragma unroll
          for(int r=0;r<4;r++){
            int ml = wm + i*16 + lk*4 + r;
            int nl = wn + j*16 + lm - g*32;
            T[nl*132 + ml] = acc[i][j][r];
          }
      }
    }
    __syncthreads();
    int nl = tid >> 3, seg = tid & 7;
    float* dst = &out[((size_t)b*DIM + n0 + g*32 + nl)*LEN + l0 + seg*16];
    #pragma unroll
    for(int k=0;k<4;k++){
      float4 v = *(const float4*)&T[nl*132 + seg*16 + k*4];
      *(float4*)&dst[k*4] = v;
    }
  }
}

extern "C" void kernel_launch(void* const* d_in, const int* in_sizes, int n_in,
                              void* d_out, int out_size, void* d_ws, size_t ws_size,
                              hipStream_t stream) {
  const float* x    = (const float*)d_in[0];
  const float* lnw  = (const float*)d_in[1];
  const float* lnb  = (const float*)d_in[2];
  const float* Win  = (const float*)d_in[3];
  const float* cw   = (const float*)d_in[4];
  const float* cb   = (const float*)d_in[5];
  const float* Wxp  = (const float*)d_in[6];
  const float* Wdt  = (const float*)d_in[7];
  const float* bdt  = (const float*)d_in[8];
  const float* Alog = (const float*)d_in[9];
  const float* Dp   = (const float*)d_in[10];
  const float* Wout = (const float*)d_in[11];
  float* out = (float*)d_out;
  float* ws  = (float*)d_ws;

  // workspace layout (float-slot offsets), total 147.25 MiB — no overlapping live ranges
  float*    mu   = ws;                          // 16384
  float*    rs   = ws + 16384;                  // 16384
  _Float16* xin  = (_Float16*)(ws + 32768);     // fp16, 16,777,216 halves (live gemm1..conv)
  _Float16* dF   = (_Float16*)(ws + 32768);     // same region, disjoint lifetime (deltag..scanC)
  float*    E    = ws + 32768 + 8388608;        // 4,194,304 fl (Hs in-place)
  float*    cum  = ws + 32768 + 12582912;       // 262,144 fl
  ushort_t* sz   = (ushort_t*)(ws + 32768 + 16777216);            // bf16 16,777,216
  ushort_t* u    = (ushort_t*)(ws + 32768 + 16777216 + 8388608);  // bf16 16,777,216 (y overwrites)
  ushort_t* xnT  = (ushort_t*)(ws + 32768 + 16777216 + 16777216); // bf16 8,388,608
  float*    dbl  = (float*)xnT;                 // alias after gemm1: 1,048,576 fp32
  ushort_t* Winb = (ushort_t*)(ws + 32768 + 16777216 + 16777216 + 4194304);
  ushort_t* Woutb= Winb + 1048576;
  ushort_t* Wxpb = Woutb + 524288;

  hipLaunchKernelGGL(ln_stats_k, dim3(256),     dim3(256), 0, stream, x, mu, rs);
  hipLaunchKernelGGL(wcvt_k,     dim3(6400),    dim3(256), 0, stream, Win, Wout, Wxp, Winb, Woutb, Wxpb);
  hipLaunchKernelGGL(xnt_k,      dim3(2048),    dim3(256), 0, stream, x, mu, rs, lnw, lnb, xnT);
  hipLaunchKernelGGL(gemm1_mfma, dim3(16,128),  dim3(256), 0, stream, xnT, Winb, xin, sz);
  hipLaunchKernelGGL(conv_silu_k,dim3(8192),    dim3(256), 0, stream, xin, cw, cb, u);
  hipLaunchKernelGGL(gemm2_mfma, dim3(128),     dim3(256), 0, stream, u, Wxpb, dbl);
  hipLaunchKernelGGL(deltag_k,   dim3(1024),    dim3(256), 0, stream, dbl, Wdt, bdt, dF);
  hipLaunchKernelGGL(scanA_k,    dim3(1024),    dim3(256), 0, stream, u, dbl, Alog, dF, E, cum);
  hipLaunchKernelGGL(scanB_k,    dim3(256),     dim3(256), 0, stream, cum, Alog, E);
  hipLaunchKernelGGL(scanC_k,    dim3(1024),    dim3(256), 0, stream, u, dbl, Alog, E, Dp, sz, dF);
  hipLaunchKernelGGL(gemm4_mfma, dim3(4,128),   dim3(256), 0, stream, u, Woutb, out);
}